// Round 7
// baseline (486.373 us; speedup 1.0000x reference)
//
#include <hip/hip_runtime.h>
#include <math.h>

// ---------------------------------------------------------------------------
// ConformerBlock on MI355X (gfx950). fp32 I/O, fp16 MFMA internals.
// B=8 T=2048 D=256 H=4 hd=64 F=1024 K=31, BT=16384.
// GEMM LDS uses XOR-swizzled column groups (swizzle applied on the GLOBAL
// fetch side, since global_load_lds scatters lane-contiguously into LDS):
// LDS slot (row, cg) holds global (row, cg ^ (row&7)); reads XOR the same key.
// ---------------------------------------------------------------------------

typedef _Float16 half8 __attribute__((ext_vector_type(8)));
typedef _Float16 half4v __attribute__((ext_vector_type(4)));
typedef float floatx4 __attribute__((ext_vector_type(4)));

#define LN_EPS 1e-5f
#define BN_SCALE 0.9999950000374996f   // 1/sqrt(1+1e-5)
#define LOG2E 1.44269504f
#define QSCALE (0.125f * LOG2E)        // folded into Q at QKV epilogue

__device__ __forceinline__ void async_copy16(const _Float16* g, _Float16* l) {
    __builtin_amdgcn_global_load_lds(
        (const __attribute__((address_space(1))) void*)g,
        (__attribute__((address_space(3))) void*)l, 16, 0, 0);
}

// ---------------------------------------------------- fused weight casts f32->f16
struct CastJobs { const float* s[7]; _Float16* d[7]; };
// segs: 4 x 262144 | qkv 196608 | out 65536 | pw2 65536  (total 1376256)
__global__ __launch_bounds__(256) void cast_all(CastJobs j) {
    int i = blockIdx.x * 256 + threadIdx.x;
    int seg, base;
    if (i < 1048576)      { seg = i >> 18; base = seg << 18; }
    else if (i < 1245184) { seg = 4; base = 1048576; }
    else if (i < 1310720) { seg = 5; base = 1245184; }
    else                  { seg = 6; base = 1310720; }
    j.d[seg][i - base] = (_Float16)j.s[seg][i - base];
}

// Permuted cast for pw1: rows interleaved in 16-row chunks [a0-15, g0-15, a16-31, ...]
__global__ __launch_bounds__(256) void cast_pw1_kernel(const float* __restrict__ w,
        const float* __restrict__ b, _Float16* __restrict__ wp, float* __restrict__ bp) {
    int i = blockIdx.x * 256 + threadIdx.x;   // 512*256 elems
    int p = i >> 8, c = i & 255;
    int chunk = p >> 4, within = p & 15;
    int orig = ((chunk & 1) ? 256 : 0) + (chunk >> 1) * 16 + within;
    wp[i] = (_Float16)w[orig * 256 + c];
    if (c == 0) bp[p] = b[orig];
}

// ------------------------------------------------------- double LayerNorm -> f16
__global__ __launch_bounds__(256) void ln2_kernel(const float* __restrict__ x,
        const float* __restrict__ g1, const float* __restrict__ b1,
        const float* __restrict__ g2, const float* __restrict__ b2,
        _Float16* __restrict__ y) {
    int wave = threadIdx.x >> 6, lane = threadIdx.x & 63;
    size_t row = (size_t)blockIdx.x * 4 + wave;
    float4 v = ((const float4*)(x + row * 256))[lane];
    float s = v.x + v.y + v.z + v.w;
    float s2 = v.x * v.x + v.y * v.y + v.z * v.z + v.w * v.w;
    #pragma unroll
    for (int m = 1; m < 64; m <<= 1) { s += __shfl_xor(s, m, 64); s2 += __shfl_xor(s2, m, 64); }
    float mean = s * (1.f / 256.f);
    float var = s2 * (1.f / 256.f) - mean * mean;
    float rs = rsqrtf(var + LN_EPS);
    int c0 = lane * 4;
    float y0 = (v.x - mean) * rs * g1[c0 + 0] + b1[c0 + 0];
    float y1 = (v.y - mean) * rs * g1[c0 + 1] + b1[c0 + 1];
    float y2 = (v.z - mean) * rs * g1[c0 + 2] + b1[c0 + 2];
    float y3 = (v.w - mean) * rs * g1[c0 + 3] + b1[c0 + 3];
    float t = y0 + y1 + y2 + y3;
    float t2 = y0 * y0 + y1 * y1 + y2 * y2 + y3 * y3;
    #pragma unroll
    for (int m = 1; m < 64; m <<= 1) { t += __shfl_xor(t, m, 64); t2 += __shfl_xor(t2, m, 64); }
    float mean2 = t * (1.f / 256.f);
    float var2 = t2 * (1.f / 256.f) - mean2 * mean2;
    float rs2 = rsqrtf(var2 + LN_EPS);
    half4v o;
    o[0] = (_Float16)((y0 - mean2) * rs2 * g2[c0 + 0] + b2[c0 + 0]);
    o[1] = (_Float16)((y1 - mean2) * rs2 * g2[c0 + 1] + b2[c0 + 1]);
    o[2] = (_Float16)((y2 - mean2) * rs2 * g2[c0 + 2] + b2[c0 + 2]);
    o[3] = (_Float16)((y3 - mean2) * rs2 * g2[c0 + 3] + b2[c0 + 3]);
    *(half4v*)(y + row * 256 + c0) = o;
}

// ---------------------------------------------------------------- GEMM (MFMA)
// 128x128 tile, BK=64, global_load_lds width-16, XOR-swizzled LDS (see header).
// EPI: 1 = swish->f16 | 2 = GLU(permuted pw1)->f16
//      5 = qkv: n<256 Q*QSCALE f16, n<512 K f16, n>=512 V^T half4 -> outv
template <int EPI>
__global__ __launch_bounds__(256) void gemm128(
        const _Float16* __restrict__ A, const _Float16* __restrict__ W,
        const float* __restrict__ bias, _Float16* __restrict__ outh,
        _Float16* __restrict__ outv, int N, int K) {
    __shared__ _Float16 As[128 * 64];
    __shared__ _Float16 Ws[128 * 64];
    int tid = threadIdx.x, wave = tid >> 6, lane = tid & 63;
    int n0 = blockIdx.x * 128, m0 = blockIdx.y * 128;
    int wr = wave >> 1, wc = wave & 1;
    floatx4 acc[4][4] = {};
    int l15 = lane & 15, quad = lane >> 4;
    int srow = wave * 32 + (lane >> 3);
    int scg  = (lane & 7) ^ ((lane >> 3) & 7);       // swizzled global col-group
    const _Float16* Aptr = A + (size_t)(m0 + srow) * K + scg * 8;
    const _Float16* Wptr = W + (size_t)(n0 + srow) * K + scg * 8;
    _Float16* AsBase = As + wave * 32 * 64;
    _Float16* WsBase = Ws + wave * 32 * 64;
    int r7 = l15 & 7;                                 // read-side swizzle key
    for (int k0 = 0; k0 < K; k0 += 64) {
        __syncthreads();
        #pragma unroll
        for (int i = 0; i < 4; i++)
            async_copy16(Aptr + k0 + (size_t)i * 8 * K, AsBase + i * 8 * 64);
        #pragma unroll
        for (int i = 0; i < 4; i++)
            async_copy16(Wptr + k0 + (size_t)i * 8 * K, WsBase + i * 8 * 64);
        __syncthreads();
        #pragma unroll
        for (int ks = 0; ks < 2; ks++) {
            int cg = ((ks * 4 + quad) ^ r7) * 8;
            half8 a[4], b[4];
            #pragma unroll
            for (int i = 0; i < 4; i++)
                a[i] = *(const half8*)&As[(wr * 64 + i * 16 + l15) * 64 + cg];
            #pragma unroll
            for (int j = 0; j < 4; j++)
                b[j] = *(const half8*)&Ws[(wc * 64 + j * 16 + l15) * 64 + cg];
            #pragma unroll
            for (int i = 0; i < 4; i++)
                #pragma unroll
                for (int j = 0; j < 4; j++)
                    acc[i][j] = __builtin_amdgcn_mfma_f32_16x16x32_f16(a[i], b[j], acc[i][j], 0, 0, 0);
        }
    }
    #pragma unroll
    for (int i = 0; i < 4; i++) {
        int mrow = m0 + wr * 64 + i * 16 + quad * 4;
        if (EPI == 2) {
            #pragma unroll
            for (int jp = 0; jp < 2; jp++) {
                int j = 2 * jp;
                int Pa = n0 + wc * 64 + j * 16 + l15;
                float ba = bias[Pa], bg = bias[Pa + 16];
                int d = ((Pa >> 5) << 4) + l15;
                #pragma unroll
                for (int r = 0; r < 4; r++) {
                    float av = acc[i][j][r] + ba;
                    float gv = acc[i][j + 1][r] + bg;
                    outh[(size_t)(mrow + r) * 256 + d] = (_Float16)(av / (1.f + __expf(-gv)));
                }
            }
        } else if (EPI == 5) {
            float qs = (n0 < 256) ? QSCALE : 1.f;
            #pragma unroll
            for (int j = 0; j < 4; j++) {
                int n = n0 + wc * 64 + j * 16 + l15;
                float bv = bias[n];
                if (n0 < 512) {
                    #pragma unroll
                    for (int r = 0; r < 4; r++)
                        outh[(size_t)(mrow + r) * N + n] = (_Float16)((acc[i][j][r] + bv) * qs);
                } else {
                    int hv = (n - 512) >> 6, d = (n - 512) & 63;
                    int bb = m0 >> 11;
                    int t0 = (m0 & 2047) + wr * 64 + i * 16 + quad * 4;
                    half4v vv;
                    #pragma unroll
                    for (int r = 0; r < 4; r++) vv[r] = (_Float16)(acc[i][j][r] + bv);
                    *(half4v*)(outv + ((size_t)((bb * 4 + hv) * 64 + d)) * 2048 + t0) = vv;
                }
            }
        } else {  // EPI == 1 swish
            #pragma unroll
            for (int j = 0; j < 4; j++) {
                int n = n0 + wc * 64 + j * 16 + l15;
                float bv = bias[n];
                #pragma unroll
                for (int r = 0; r < 4; r++) {
                    float c = acc[i][j][r] + bv;
                    outh[(size_t)(mrow + r) * N + n] = (_Float16)(c / (1.f + __expf(-c)));
                }
            }
        }
    }
}

// ------------------------------------------------- full-row reducer GEMM (N=256)
// tile 64x256 (4 waves x 64x64), XOR-swizzled LDS. Epilogue: c += bias;
// x = res + alpha*c;
// FIN=0: write xNext f32, then t16 = LN(LN(x; g1,b1); g2,b2) f16.
// FIN=1: write finalOut f32 = LN(x; g1,b1)  (d_out path, no xNext).
template <int FIN>
__global__ __launch_bounds__(256) void gemm_row(
        const _Float16* __restrict__ A, const _Float16* __restrict__ W,
        const float* __restrict__ bias, const float* __restrict__ res, float alpha,
        float* __restrict__ xNext, _Float16* __restrict__ t16out,
        float* __restrict__ finalOut,
        const float* __restrict__ g1, const float* __restrict__ b1,
        const float* __restrict__ g2, const float* __restrict__ b2, int K) {
    __shared__ _Float16 As[64 * 64];    // 8 KB
    __shared__ _Float16 Ws[256 * 64];   // 32 KB
    __shared__ float red[4][64][2];     // per-wave per-row (s1,s2)
    int tid = threadIdx.x, wave = tid >> 6, lane = tid & 63;
    int l15 = lane & 15, quad = lane >> 4;
    int m0 = blockIdx.x * 64;
    int sgsw = (tid & 7) ^ ((tid >> 3) & 7);          // swizzled global col-group
    int r7 = l15 & 7;
    floatx4 acc[4][4] = {};
    for (int k0 = 0; k0 < K; k0 += 64) {
        __syncthreads();
        #pragma unroll
        for (int i = 0; i < 2; i++) {
            int idx = tid + 256 * i;
            async_copy16(A + (size_t)(m0 + (idx >> 3)) * K + k0 + sgsw * 8, As + idx * 8);
        }
        #pragma unroll
        for (int i = 0; i < 8; i++) {
            int idx = tid + 256 * i;
            async_copy16(W + (size_t)(idx >> 3) * K + k0 + sgsw * 8, Ws + idx * 8);
        }
        __syncthreads();
        #pragma unroll
        for (int ks = 0; ks < 2; ks++) {
            int cg = ((ks * 4 + quad) ^ r7) * 8;
            half8 a[4], b[4];
            #pragma unroll
            for (int i = 0; i < 4; i++)
                a[i] = *(const half8*)&As[(i * 16 + l15) * 64 + cg];
            #pragma unroll
            for (int j = 0; j < 4; j++)
                b[j] = *(const half8*)&Ws[(wave * 64 + j * 16 + l15) * 64 + cg];
            #pragma unroll
            for (int i = 0; i < 4; i++)
                #pragma unroll
                for (int j = 0; j < 4; j++)
                    acc[i][j] = __builtin_amdgcn_mfma_f32_16x16x32_f16(a[i], b[j], acc[i][j], 0, 0, 0);
        }
    }
    // ---- epilogue: bias + residual
    int col[4];
    float bv[4], gg1[4], bb1[4], gg2[4], bb2[4];
    #pragma unroll
    for (int j = 0; j < 4; j++) {
        col[j] = wave * 64 + j * 16 + l15;
        bv[j] = bias[col[j]];
        gg1[j] = g1[col[j]]; bb1[j] = b1[col[j]];
        if (FIN == 0) { gg2[j] = g2[col[j]]; bb2[j] = b2[col[j]]; }
    }
    #pragma unroll
    for (int i = 0; i < 4; i++)
        #pragma unroll
        for (int r = 0; r < 4; r++) {
            size_t m = m0 + i * 16 + quad * 4 + r;
            #pragma unroll
            for (int j = 0; j < 4; j++) {
                float xv = res[m * 256 + col[j]] + alpha * (acc[i][j][r] + bv[j]);
                acc[i][j][r] = xv;
                if (FIN == 0) xNext[m * 256 + col[j]] = xv;
            }
        }
    // ---- LN pass 1 stats
    #pragma unroll
    for (int i = 0; i < 4; i++)
        #pragma unroll
        for (int r = 0; r < 4; r++) {
            float s1 = 0.f, s2 = 0.f;
            #pragma unroll
            for (int j = 0; j < 4; j++) { float v = acc[i][j][r]; s1 += v; s2 += v * v; }
            #pragma unroll
            for (int mm = 1; mm < 16; mm <<= 1) { s1 += __shfl_xor(s1, mm, 64); s2 += __shfl_xor(s2, mm, 64); }
            if (l15 == 0) { red[wave][i * 16 + quad * 4 + r][0] = s1; red[wave][i * 16 + quad * 4 + r][1] = s2; }
        }
    __syncthreads();
    float mean1[4][4], rs1[4][4];
    #pragma unroll
    for (int i = 0; i < 4; i++)
        #pragma unroll
        for (int r = 0; r < 4; r++) {
            int row = i * 16 + quad * 4 + r;
            float T1 = red[0][row][0] + red[1][row][0] + red[2][row][0] + red[3][row][0];
            float T2 = red[0][row][1] + red[1][row][1] + red[2][row][1] + red[3][row][1];
            float mn = T1 * (1.f / 256.f);
            mean1[i][r] = mn;
            rs1[i][r] = rsqrtf(T2 * (1.f / 256.f) - mn * mn + LN_EPS);
        }
    if (FIN == 1) {
        #pragma unroll
        for (int i = 0; i < 4; i++)
            #pragma unroll
            for (int r = 0; r < 4; r++) {
                size_t m = m0 + i * 16 + quad * 4 + r;
                #pragma unroll
                for (int j = 0; j < 4; j++)
                    finalOut[m * 256 + col[j]] =
                        (acc[i][j][r] - mean1[i][r]) * rs1[i][r] * gg1[j] + bb1[j];
            }
        return;
    }
    // y1 in-place, then pass 2 stats
    #pragma unroll
    for (int i = 0; i < 4; i++)
        #pragma unroll
        for (int r = 0; r < 4; r++)
            #pragma unroll
            for (int j = 0; j < 4; j++)
                acc[i][j][r] = (acc[i][j][r] - mean1[i][r]) * rs1[i][r] * gg1[j] + bb1[j];
    __syncthreads();
    #pragma unroll
    for (int i = 0; i < 4; i++)
        #pragma unroll
        for (int r = 0; r < 4; r++) {
            float s1 = 0.f, s2 = 0.f;
            #pragma unroll
            for (int j = 0; j < 4; j++) { float v = acc[i][j][r]; s1 += v; s2 += v * v; }
            #pragma unroll
            for (int mm = 1; mm < 16; mm <<= 1) { s1 += __shfl_xor(s1, mm, 64); s2 += __shfl_xor(s2, mm, 64); }
            if (l15 == 0) { red[wave][i * 16 + quad * 4 + r][0] = s1; red[wave][i * 16 + quad * 4 + r][1] = s2; }
        }
    __syncthreads();
    #pragma unroll
    for (int i = 0; i < 4; i++)
        #pragma unroll
        for (int r = 0; r < 4; r++) {
            int row = i * 16 + quad * 4 + r;
            float T1 = red[0][row][0] + red[1][row][0] + red[2][row][0] + red[3][row][0];
            float T2 = red[0][row][1] + red[1][row][1] + red[2][row][1] + red[3][row][1];
            float mn = T1 * (1.f / 256.f);
            float rs = rsqrtf(T2 * (1.f / 256.f) - mn * mn + LN_EPS);
            size_t m = m0 + row;
            #pragma unroll
            for (int j = 0; j < 4; j++)
                t16out[m * 256 + col[j]] =
                    (_Float16)((acc[i][j][r] - mn) * rs * gg2[j] + bb2[j]);
        }
}

// --------------------------------- relative position bias (exp2 domain: *log2e)
__global__ __launch_bounds__(256) void relbias_kernel(const float* __restrict__ rel_w,
                                                      float* __restrict__ rb) {
    int i = blockIdx.x * 256 + threadIdx.x;
    if (i >= 4095 * 4) return;
    int p = i >> 2, h = i & 3;
    float pos = (float)(p - 2047);
    const float c = -logf(10000.f) / 64.f;
    float acc = 0.f;
    for (int k = 0; k < 32; k++) {
        float dv = expf((float)(2 * k) * c);
        float ang = pos * dv;
        acc += sinf(ang) * rel_w[h * 64 + 2 * k] + cosf(ang) * rel_w[h * 64 + 2 * k + 1];
    }
    rb[h * 4095 + p] = acc * LOG2E;
}

// ----------------------------------------------------------- flash attention v5
// 128 q-rows x 64-key tiles, K-SPLIT x2 (additive partials, max-free softmax).
__global__ __launch_bounds__(256) void attn_kernel(const _Float16* __restrict__ qkv,
        const _Float16* __restrict__ vtg, const float* __restrict__ rb,
        float* __restrict__ opart, float* __restrict__ lpart) {
    const int T = 2048;
    int qt = blockIdx.x & 15, ksp = blockIdx.x >> 4, h = blockIdx.y, b = blockIdx.z;
    int tid = threadIdx.x, wave = tid >> 6, lane = tid & 63;
    __shared__ __align__(16) _Float16 PQ[128 * 72];       // Qs[128][72] ∪ Ps[4][32][72]
    __shared__ __align__(16) _Float16 Ks[64][72];
    __shared__ __align__(16) _Float16 Vt[64][72];         // [d][key]
    __shared__ __align__(16) float bias4[4][192];         // bias4[c][i] = w[i+c]
    auto Qs = (_Float16(*)[72])PQ;
    auto Ps = (_Float16(*)[32][72])PQ;

    int l15 = lane & 15, quad = lane >> 4, kq = quad * 8;
    size_t qrow0 = (size_t)b * T + qt * 128;
    #pragma unroll
    for (int i = 0; i < 4; i++) {
        int idx = tid + 256 * i, r = idx >> 3, sg = idx & 7;
        *(float4*)(&Qs[r][sg * 8]) = *(const float4*)(qkv + (qrow0 + r) * 768 + h * 64 + sg * 8);
    }
    __syncthreads();
    half8 qa[2][2];
    #pragma unroll
    for (int u = 0; u < 2; u++)
        #pragma unroll
        for (int ks = 0; ks < 2; ks++)
            qa[u][ks] = *(const half8*)(&Qs[u * 64 + wave * 16 + l15][ks * 32 + kq]);
    half8 ones;
    #pragma unroll
    for (int j = 0; j < 8; j++) ones[j] = (_Float16)1.f;

    floatx4 oacc[2][4] = {};
    floatx4 lacc[2] = {};
    const float* rbh = rb + h * 4095;
    const _Float16* vbase = vtg + ((size_t)(b * 4 + h)) * 64 * 2048;
    const _Float16* kbase = qkv + ((size_t)b * T) * 768 + 256 + h * 64;
    int cshift = (63 - l15) & 3;

    for (int kt = ksp * 16; kt < ksp * 16 + 16; kt++) {
        __syncthreads();
        #pragma unroll
        for (int i = 0; i < 2; i++) {
            int idx = tid + 256 * i, r = idx >> 3, sg = idx & 7;
            *(float4*)(&Ks[r][sg * 8]) = *(const float4*)(kbase + (size_t)(kt * 64 + r) * 768 + sg * 8);
            *(float4*)(&Vt[r][sg * 8]) = *(const float4*)(vbase + (size_t)r * 2048 + kt * 64 + sg * 8);
        }
        if (tid < 192) {
            int base = qt * 128 - kt * 64 + 1984;
            float v = rbh[min(base + tid, 4094)];
            #pragma unroll
            for (int c = 0; c < 4; c++) {
                int idx = tid - c;
                if (idx >= 0) bias4[c][idx] = v;
            }
        }
        __syncthreads();
        half8 kf[2][4];
        #pragma unroll
        for (int ks = 0; ks < 2; ks++)
            #pragma unroll
            for (int nt = 0; nt < 4; nt++)
                kf[ks][nt] = *(const half8*)(&Ks[nt * 16 + l15][ks * 32 + kq]);
        floatx4 s[2][4];
        #pragma unroll
        for (int u = 0; u < 2; u++)
            #pragma unroll
            for (int nt = 0; nt < 4; nt++) {
                int cb = u * 64 + wave * 16 + quad * 4 - (nt * 16 + l15) + 63;
                s[u][nt] = *(const floatx4*)&bias4[cshift][cb - cshift];
            }
        #pragma unroll
        for (int u = 0; u < 2; u++)
            #pragma unroll
            for (int ks = 0; ks < 2; ks++)
                #pragma unroll
                for (int nt = 0; nt < 4; nt++)
                    s[u][nt] = __builtin_amdgcn_mfma_f32_16x16x32_f16(qa[u][ks], kf[ks][nt], s[u][nt], 0, 0, 0);
        #pragma unroll
        for (int u = 0; u < 2; u++)
            #pragma unroll
            for (int nt = 0; nt < 4; nt++)
                #pragma unroll
                for (int r = 0; r < 4; r++)
                    Ps[wave][u * 16 + quad * 4 + r][nt * 16 + l15] =
                        (_Float16)__builtin_amdgcn_exp2f(fminf(s[u][nt][r], 15.86f));
        half8 vf[2][4];
        #pragma unroll
        for (int ks = 0; ks < 2; ks++)
            #pragma unroll
            for (int nt = 0; nt < 4; nt++)
                vf[ks][nt] = *(const half8*)(&Vt[nt * 16 + l15][ks * 32 + kq]);
        #pragma unroll
        for (int u = 0; u < 2; u++)
            #pragma unroll
            for (int ks = 0; ks < 2; ks++) {
                half8 pa = *(const half8*)(&Ps[wave][u * 16 + l15][ks * 32 + kq]);
                lacc[u] = __builtin_amdgcn_mfma_f32_16x16x32_f16(pa, ones, lacc[u], 0, 0, 0);
                #pragma unroll
                for (int nt = 0; nt < 4; nt++)
                    oacc[u][nt] = __builtin_amdgcn_mfma_f32_16x16x32_f16(pa, vf[ks][nt], oacc[u][nt], 0, 0, 0);
            }
    }
    float* obase = opart + (size_t)ksp * 16384 * 256;
    #pragma unroll
    for (int u = 0; u < 2; u++) {
        size_t orow0 = qrow0 + u * 64 + wave * 16 + quad * 4;
        #pragma unroll
        for (int r = 0; r < 4; r++)
            #pragma unroll
            for (int nt = 0; nt < 4; nt++)
                obase[(orow0 + r) * 256 + h * 64 + nt * 16 + l15] = oacc[u][nt][r];
        if (l15 == 0) {
            int q = qt * 128 + u * 64 + wave * 16 + quad * 4;
            float* lp = lpart + ksp * 65536 + ((b * 4 + h) << 11) + q;
            #pragma unroll
            for (int r = 0; r < 4; r++) lp[r] = lacc[u][r];
        }
    }
}

// ------------------------------------------ combine K-split partials -> o16
__global__ __launch_bounds__(256) void attn_combine(const float* __restrict__ opart,
        const float* __restrict__ lpart, _Float16* __restrict__ o16) {
    int wave = threadIdx.x >> 6, lane = threadIdx.x & 63;
    size_t row = (size_t)blockIdx.x * 4 + wave;
    int c0 = lane * 4;
    float4 a = ((const float4*)(opart + row * 256))[lane];
    float4 bq = ((const float4*)(opart + (size_t)16384 * 256 + row * 256))[lane];
    int b = (int)(row >> 11), q = (int)(row & 2047), h = c0 >> 6;
    int li = ((b * 4 + h) << 11) + q;
    float inv = 1.f / (lpart[li] + lpart[65536 + li]);
    half4v o;
    o[0] = (_Float16)((a.x + bq.x) * inv);
    o[1] = (_Float16)((a.y + bq.y) * inv);
    o[2] = (_Float16)((a.z + bq.z) * inv);
    o[3] = (_Float16)((a.w + bq.w) * inv);
    *(half4v*)(o16 + row * 256 + c0) = o;
}

// -------------------------------------------- depthwise conv 31 + BN + swish
// grid (64,8)=512 blocks, 32 t/block, 4-wide batched prefetch.
__global__ __launch_bounds__(256) void dwconv_kernel(const _Float16* __restrict__ glu,
        const float* __restrict__ dw_w, const float* __restrict__ dw_b,
        const float* __restrict__ bn_g, const float* __restrict__ bn_b,
        _Float16* __restrict__ out) {
    const int T = 2048;
    int d = threadIdx.x;
    int b = blockIdx.y, t0 = blockIdx.x * 32;
    const _Float16* base = glu + ((size_t)b * T) * 256 + d;
    float w[31], win[31];
    #pragma unroll
    for (int j = 0; j < 31; j++) w[j] = dw_w[d * 31 + j];
    #pragma unroll
    for (int j = 0; j < 31; j++) {
        int tt = t0 - 15 + j;
        win[j] = (tt >= 0 && tt < T) ? (float)base[(size_t)tt * 256] : 0.f;
    }
    float dwb = dw_b[d];
    float bns = BN_SCALE * bn_g[d];
    float bnb = bn_b[d];
    size_t orow = ((size_t)b * T) * 256 + d;
    #pragma unroll
    for (int i = 0; i < 32; i += 4) {
        float nl[4];
        #pragma unroll
        for (int u = 0; u < 4; u++) {
            int tn = t0 + i + u + 16;
            nl[u] = (tn < T) ? (float)base[(size_t)tn * 256] : 0.f;
        }
        #pragma unroll
        for (int u = 0; u < 4; u++) {
            int t = t0 + i + u;
            float acc = dwb;
            #pragma unroll
            for (int j = 0; j < 31; j++) acc += win[j] * w[j];
            float bn = acc * bns + bnb;
            out[orow + (size_t)t * 256] = (_Float16)(bn / (1.f + __expf(-bn)));
            #pragma unroll
            for (int j = 0; j < 30; j++) win[j] = win[j + 1];
            win[30] = nl[u];
        }
    }
}

// ---------------------------------------------------------------------------
extern "C" void kernel_launch(void* const* d_in, const int* in_sizes, int n_in,
                              void* d_out, int out_size, void* d_ws, size_t ws_size,
                              hipStream_t stream) {
    (void)in_sizes; (void)n_in; (void)out_size; (void)ws_size;
    const float* x      = (const float*)d_in[0];
    const float* g_ffn1 = (const float*)d_in[1];
    const float* g_mhsa = (const float*)d_in[2];
    const float* g_conv = (const float*)d_in[3];
    const float* g_ffn2 = (const float*)d_in[4];
    const float* g_out  = (const float*)d_in[5];
    const float* f1_ng  = (const float*)d_in[6];
    const float* f2_ng  = (const float*)d_in[7];
    const float* a_ng   = (const float*)d_in[8];
    const float* c_ng   = (const float*)d_in[9];
    const float* bn_g   = (const float*)d_in[10];
    const float* b_ffn1 = (const float*)d_in[11];
    const float* b_mhsa = (const float*)d_in[12];
    const float* b_conv = (const float*)d_in[13];
    const float* b_ffn2 = (const float*)d_in[14];
    const float* b_out  = (const float*)d_in[15];
    const float* f1_nb  = (const float*)d_in[16];
    const float* f2_nb  = (const float*)d_in[17];
    const float* a_nb   = (const float*)d_in[18];
    const float* c_nb   = (const float*)d_in[19];
    const float* bn_b   = (const float*)d_in[20];
    const float* f1_w1  = (const float*)d_in[21];
    const float* f1_b1  = (const float*)d_in[22];
    const float* f1_w2  = (const float*)d_in[23];
    const float* f1_b2  = (const float*)d_in[24];
    const float* f2_w1  = (const float*)d_in[25];
    const float* f2_b1  = (const float*)d_in[26];
    const float* f2_w2  = (const float*)d_in[27];
    const float* f2_b2  = (const float*)d_in[28];
    const float* qkv_w  = (const float*)d_in[29];
    const float* qkv_b  = (const float*)d_in[30];
    const float* rel_w  = (const float*)d_in[31];
    const float* out_w  = (const float*)d_in[32];
    const float* out_b  = (const float*)d_in[33];
    const float* pw1_w  = (const float*)d_in[34];
    const float* pw1_b  = (const float*)d_in[35];
    const float* dw_w   = (const float*)d_in[36];
    const float* dw_b   = (const float*)d_in[37];
    const float* pw2_w  = (const float*)d_in[38];
    const float* pw2_b  = (const float*)d_in[39];

    const int BT = 16384;
    char* ws = (char*)d_ws;
    size_t off = 0;
    auto alloc = [&](size_t bytes) -> char* {
        char* p = ws + off;
        off += (bytes + 255) & ~(size_t)255;
        return p;
    };
    _Float16* wf1w1 = (_Float16*)alloc(262144 * 2);
    _Float16* wf1w2 = (_Float16*)alloc(262144 * 2);
    _Float16* wf2w1 = (_Float16*)alloc(262144 * 2);
    _Float16* wf2w2 = (_Float16*)alloc(262144 * 2);
    _Float16* wqkv  = (_Float16*)alloc(196608 * 2);
    _Float16* wout  = (_Float16*)alloc(65536 * 2);
    _Float16* wpw1  = (_Float16*)alloc(131072 * 2);
    float* pb1      = (float*)alloc(512 * 4);
    _Float16* wpw2  = (_Float16*)alloc(65536 * 2);
    float* rbbuf    = (float*)alloc(4 * 4095 * 4);
    float* xA       = (float*)alloc((size_t)BT * 256 * 4);
    float* xB       = (float*)alloc((size_t)BT * 256 * 4);
    _Float16* t16   = (_Float16*)alloc((size_t)BT * 256 * 2);
    char* R1        = alloc((size_t)BT * 1024 * 2);  // h16 (32MB) / qkv16 (24MB)
    _Float16* vtg   = (_Float16*)alloc((size_t)8 * 4 * 64 * 2048 * 2);  // V^T [b,h,d][t]
    float* opart    = (float*)alloc((size_t)2 * BT * 256 * 4);          // K-split O partials
    float* lpart    = (float*)alloc((size_t)2 * 65536 * 4);             // K-split l partials
    _Float16* glu16 = (_Float16*)alloc((size_t)BT * 256 * 2);
    _Float16* c16   = (_Float16*)alloc((size_t)BT * 256 * 2);
    _Float16* o16   = (_Float16*)alloc((size_t)BT * 256 * 2);
    _Float16* h16   = (_Float16*)R1;
    _Float16* qkv16 = (_Float16*)R1;

    // fused weight casts + pw1 permute + rel-pos bias table
    CastJobs cj;
    cj.s[0] = f1_w1; cj.d[0] = wf1w1;
    cj.s[1] = f1_w2; cj.d[1] = wf1w2;
    cj.s[2] = f2_w1; cj.d[2] = wf2w1;
    cj.s[3] = f2_w2; cj.d[3] = wf2w2;
    cj.s[4] = qkv_w; cj.d[4] = wqkv;
    cj.s[5] = out_w; cj.d[5] = wout;
    cj.s[6] = pw2_w; cj.d[6] = wpw2;
    cast_all<<<5376, 256, 0, stream>>>(cj);
    cast_pw1_kernel<<<512, 256, 0, stream>>>(pw1_w, pw1_b, wpw1, pb1);
    relbias_kernel<<<64, 256, 0, stream>>>(rel_w, rbbuf);

    // ---- FFN1: x1 = x + 0.5*FFN(LN2(x)); fused: t16 = LN2(x1) for MHSA
    ln2_kernel<<<BT / 4, 256, 0, stream>>>(x, g_ffn1, b_ffn1, f1_ng, f1_nb, t16);
    gemm128<1><<<dim3(8, 128), 256, 0, stream>>>(t16, wf1w1, f1_b1, h16, nullptr, 1024, 256);
    gemm_row<0><<<256, 256, 0, stream>>>(h16, wf1w2, f1_b2, x, 0.5f, xA, t16, nullptr,
                                         g_mhsa, b_mhsa, a_ng, a_nb, 1024);
    // ---- MHSA: x2 = x1 + Attn(t16); fused: t16 = LN2(x2) for Conv
    gemm128<5><<<dim3(6, 128), 256, 0, stream>>>(t16, wqkv, qkv_b, qkv16, vtg, 768, 256);
    attn_kernel<<<dim3(32, 4, 8), 256, 0, stream>>>(qkv16, vtg, rbbuf, opart, lpart);
    attn_combine<<<BT / 4, 256, 0, stream>>>(opart, lpart, o16);
    gemm_row<0><<<256, 256, 0, stream>>>(o16, wout, out_b, xA, 1.f, xB, t16, nullptr,
                                         g_conv, b_conv, c_ng, c_nb, 256);
    // ---- Conv: x3 = x2 + Conv(t16); fused: t16 = LN2(x3) for FFN2
    gemm128<2><<<dim3(4, 128), 256, 0, stream>>>(t16, wpw1, pb1, glu16, nullptr, 512, 256);
    dwconv_kernel<<<dim3(64, 8), 256, 0, stream>>>(glu16, dw_w, dw_b, bn_g, bn_b, c16);
    gemm_row<0><<<256, 256, 0, stream>>>(c16, wpw2, pw2_b, xB, 1.f, xA, t16, nullptr,
                                         g_ffn2, b_ffn2, f2_ng, f2_nb, 256);
    // ---- FFN2 + final LN: out = LN(x3 + 0.5*FFN(t16))
    gemm128<1><<<dim3(8, 128), 256, 0, stream>>>(t16, wf2w1, f2_b1, h16, nullptr, 1024, 256);
    gemm_row<1><<<256, 256, 0, stream>>>(h16, wf2w2, f2_b2, xA, 0.5f, nullptr, nullptr,
                                         (float*)d_out, g_out, b_out, nullptr, nullptr, 1024);
}

// Round 8
// 455.079 us; speedup vs baseline: 1.0688x; 1.0688x over previous
//
#include <hip/hip_runtime.h>
#include <math.h>

// ---------------------------------------------------------------------------
// ConformerBlock on MI355X (gfx950). fp32 I/O, fp16 MFMA internals.
// B=8 T=2048 D=256 H=4 hd=64 F=1024 K=31, BT=16384.
// ---------------------------------------------------------------------------

typedef _Float16 half8 __attribute__((ext_vector_type(8)));
typedef _Float16 half4v __attribute__((ext_vector_type(4)));
typedef float floatx4 __attribute__((ext_vector_type(4)));

#define LN_EPS 1e-5f
#define BN_SCALE 0.9999950000374996f   // 1/sqrt(1+1e-5)
#define LOG2E 1.44269504f
#define QSCALE (0.125f * LOG2E)        // folded into Q at QKV epilogue

__device__ __forceinline__ void async_copy16(const _Float16* g, _Float16* l) {
    __builtin_amdgcn_global_load_lds(
        (const __attribute__((address_space(1))) void*)g,
        (__attribute__((address_space(3))) void*)l, 16, 0, 0);
}

// ---------------------------------------------------- fused weight casts f32->f16
struct CastJobs { const float* s[7]; _Float16* d[7]; };
// segs: 4 x 262144 | qkv 196608 | out 65536 | pw2 65536  (total 1376256)
__global__ __launch_bounds__(256) void cast_all(CastJobs j) {
    int i = blockIdx.x * 256 + threadIdx.x;
    int seg, base;
    if (i < 1048576)      { seg = i >> 18; base = seg << 18; }
    else if (i < 1245184) { seg = 4; base = 1048576; }
    else if (i < 1310720) { seg = 5; base = 1245184; }
    else                  { seg = 6; base = 1310720; }
    j.d[seg][i - base] = (_Float16)j.s[seg][i - base];
}

// Permuted cast for pw1: rows interleaved in 16-row chunks [a0-15, g0-15, a16-31, ...]
__global__ __launch_bounds__(256) void cast_pw1_kernel(const float* __restrict__ w,
        const float* __restrict__ b, _Float16* __restrict__ wp, float* __restrict__ bp) {
    int i = blockIdx.x * 256 + threadIdx.x;   // 512*256 elems
    int p = i >> 8, c = i & 255;
    int chunk = p >> 4, within = p & 15;
    int orig = ((chunk & 1) ? 256 : 0) + (chunk >> 1) * 16 + within;
    wp[i] = (_Float16)w[orig * 256 + c];
    if (c == 0) bp[p] = b[orig];
}

// ------------------------------------------------------- double LayerNorm -> f16
__global__ __launch_bounds__(256) void ln2_kernel(const float* __restrict__ x,
        const float* __restrict__ g1, const float* __restrict__ b1,
        const float* __restrict__ g2, const float* __restrict__ b2,
        _Float16* __restrict__ y) {
    int wave = threadIdx.x >> 6, lane = threadIdx.x & 63;
    size_t row = (size_t)blockIdx.x * 4 + wave;
    float4 v = ((const float4*)(x + row * 256))[lane];
    float s = v.x + v.y + v.z + v.w;
    float s2 = v.x * v.x + v.y * v.y + v.z * v.z + v.w * v.w;
    #pragma unroll
    for (int m = 1; m < 64; m <<= 1) { s += __shfl_xor(s, m, 64); s2 += __shfl_xor(s2, m, 64); }
    float mean = s * (1.f / 256.f);
    float var = s2 * (1.f / 256.f) - mean * mean;
    float rs = rsqrtf(var + LN_EPS);
    int c0 = lane * 4;
    float y0 = (v.x - mean) * rs * g1[c0 + 0] + b1[c0 + 0];
    float y1 = (v.y - mean) * rs * g1[c0 + 1] + b1[c0 + 1];
    float y2 = (v.z - mean) * rs * g1[c0 + 2] + b1[c0 + 2];
    float y3 = (v.w - mean) * rs * g1[c0 + 3] + b1[c0 + 3];
    float t = y0 + y1 + y2 + y3;
    float t2 = y0 * y0 + y1 * y1 + y2 * y2 + y3 * y3;
    #pragma unroll
    for (int m = 1; m < 64; m <<= 1) { t += __shfl_xor(t, m, 64); t2 += __shfl_xor(t2, m, 64); }
    float mean2 = t * (1.f / 256.f);
    float var2 = t2 * (1.f / 256.f) - mean2 * mean2;
    float rs2 = rsqrtf(var2 + LN_EPS);
    half4v o;
    o[0] = (_Float16)((y0 - mean2) * rs2 * g2[c0 + 0] + b2[c0 + 0]);
    o[1] = (_Float16)((y1 - mean2) * rs2 * g2[c0 + 1] + b2[c0 + 1]);
    o[2] = (_Float16)((y2 - mean2) * rs2 * g2[c0 + 2] + b2[c0 + 2]);
    o[3] = (_Float16)((y3 - mean2) * rs2 * g2[c0 + 3] + b2[c0 + 3]);
    *(half4v*)(y + row * 256 + c0) = o;
}

// ---------------------------------------------------------------- GEMM (MFMA)
// 128x128 tile, BK=64, global_load_lds width-16, XOR-swizzled LDS col-groups.
// EPI: 1 = swish->f16 | 2 = GLU(permuted pw1)->f16
//      5 = qkv: n<256 Q*QSCALE f16, n<512 K f16, n>=512 V^T half4 -> outv
template <int EPI>
__global__ __launch_bounds__(256) void gemm128(
        const _Float16* __restrict__ A, const _Float16* __restrict__ W,
        const float* __restrict__ bias, _Float16* __restrict__ outh,
        _Float16* __restrict__ outv, int N, int K) {
    __shared__ _Float16 As[128 * 64];
    __shared__ _Float16 Ws[128 * 64];
    int tid = threadIdx.x, wave = tid >> 6, lane = tid & 63;
    int n0 = blockIdx.x * 128, m0 = blockIdx.y * 128;
    int wr = wave >> 1, wc = wave & 1;
    floatx4 acc[4][4] = {};
    int l15 = lane & 15, quad = lane >> 4;
    int srow = wave * 32 + (lane >> 3);
    int scg  = (lane & 7) ^ ((lane >> 3) & 7);       // swizzled global col-group
    const _Float16* Aptr = A + (size_t)(m0 + srow) * K + scg * 8;
    const _Float16* Wptr = W + (size_t)(n0 + srow) * K + scg * 8;
    _Float16* AsBase = As + wave * 32 * 64;
    _Float16* WsBase = Ws + wave * 32 * 64;
    int r7 = l15 & 7;                                 // read-side swizzle key
    for (int k0 = 0; k0 < K; k0 += 64) {
        __syncthreads();
        #pragma unroll
        for (int i = 0; i < 4; i++)
            async_copy16(Aptr + k0 + (size_t)i * 8 * K, AsBase + i * 8 * 64);
        #pragma unroll
        for (int i = 0; i < 4; i++)
            async_copy16(Wptr + k0 + (size_t)i * 8 * K, WsBase + i * 8 * 64);
        __syncthreads();
        #pragma unroll
        for (int ks = 0; ks < 2; ks++) {
            int cg = ((ks * 4 + quad) ^ r7) * 8;
            half8 a[4], b[4];
            #pragma unroll
            for (int i = 0; i < 4; i++)
                a[i] = *(const half8*)&As[(wr * 64 + i * 16 + l15) * 64 + cg];
            #pragma unroll
            for (int j = 0; j < 4; j++)
                b[j] = *(const half8*)&Ws[(wc * 64 + j * 16 + l15) * 64 + cg];
            #pragma unroll
            for (int i = 0; i < 4; i++)
                #pragma unroll
                for (int j = 0; j < 4; j++)
                    acc[i][j] = __builtin_amdgcn_mfma_f32_16x16x32_f16(a[i], b[j], acc[i][j], 0, 0, 0);
        }
    }
    #pragma unroll
    for (int i = 0; i < 4; i++) {
        int mrow = m0 + wr * 64 + i * 16 + quad * 4;
        if (EPI == 2) {
            #pragma unroll
            for (int jp = 0; jp < 2; jp++) {
                int j = 2 * jp;
                int Pa = n0 + wc * 64 + j * 16 + l15;
                float ba = bias[Pa], bg = bias[Pa + 16];
                int d = ((Pa >> 5) << 4) + l15;
                #pragma unroll
                for (int r = 0; r < 4; r++) {
                    float av = acc[i][j][r] + ba;
                    float gv = acc[i][j + 1][r] + bg;
                    outh[(size_t)(mrow + r) * 256 + d] = (_Float16)(av / (1.f + __expf(-gv)));
                }
            }
        } else if (EPI == 5) {
            float qs = (n0 < 256) ? QSCALE : 1.f;
            #pragma unroll
            for (int j = 0; j < 4; j++) {
                int n = n0 + wc * 64 + j * 16 + l15;
                float bv = bias[n];
                if (n0 < 512) {
                    #pragma unroll
                    for (int r = 0; r < 4; r++)
                        outh[(size_t)(mrow + r) * N + n] = (_Float16)((acc[i][j][r] + bv) * qs);
                } else {
                    int hv = (n - 512) >> 6, d = (n - 512) & 63;
                    int bb = m0 >> 11;
                    int t0 = (m0 & 2047) + wr * 64 + i * 16 + quad * 4;
                    half4v vv;
                    #pragma unroll
                    for (int r = 0; r < 4; r++) vv[r] = (_Float16)(acc[i][j][r] + bv);
                    *(half4v*)(outv + ((size_t)((bb * 4 + hv) * 64 + d)) * 2048 + t0) = vv;
                }
            }
        } else {  // EPI == 1 swish
            #pragma unroll
            for (int j = 0; j < 4; j++) {
                int n = n0 + wc * 64 + j * 16 + l15;
                float bv = bias[n];
                #pragma unroll
                for (int r = 0; r < 4; r++) {
                    float c = acc[i][j][r] + bv;
                    outh[(size_t)(mrow + r) * N + n] = (_Float16)(c / (1.f + __expf(-c)));
                }
            }
        }
    }
}

// ------------------------------------------------- full-row reducer GEMM (N=256)
// tile 32x256 (4 waves x 32x64), grid 512 = 2 blocks/CU. Epilogue: c += bias;
// x = res + alpha*c;
// FIN=0: write xNext f32, then t16 = LN(LN(x; g1,b1); g2,b2) f16.
// FIN=1: write finalOut f32 = LN(x; g1,b1)  (d_out path, no xNext).
template <int FIN>
__global__ __launch_bounds__(256) void gemm_row(
        const _Float16* __restrict__ A, const _Float16* __restrict__ W,
        const float* __restrict__ bias, const float* __restrict__ res, float alpha,
        float* __restrict__ xNext, _Float16* __restrict__ t16out,
        float* __restrict__ finalOut,
        const float* __restrict__ g1, const float* __restrict__ b1,
        const float* __restrict__ g2, const float* __restrict__ b2, int K) {
    __shared__ _Float16 As[32 * 64];    // 4 KB
    __shared__ _Float16 Ws[256 * 64];   // 32 KB
    __shared__ float red[4][32][2];     // per-wave per-row (s1,s2)
    int tid = threadIdx.x, wave = tid >> 6, lane = tid & 63;
    int l15 = lane & 15, quad = lane >> 4;
    int m0 = blockIdx.x * 32;
    int sgsw = (tid & 7) ^ ((tid >> 3) & 7);          // swizzled global col-group
    int r7 = l15 & 7;
    floatx4 acc[2][4] = {};
    for (int k0 = 0; k0 < K; k0 += 64) {
        __syncthreads();
        async_copy16(A + (size_t)(m0 + (tid >> 3)) * K + k0 + sgsw * 8, As + tid * 8);
        #pragma unroll
        for (int i = 0; i < 8; i++) {
            int idx = tid + 256 * i;
            async_copy16(W + (size_t)(idx >> 3) * K + k0 + sgsw * 8, Ws + idx * 8);
        }
        __syncthreads();
        #pragma unroll
        for (int ks = 0; ks < 2; ks++) {
            int cg = ((ks * 4 + quad) ^ r7) * 8;
            half8 a[2], b[4];
            #pragma unroll
            for (int i = 0; i < 2; i++)
                a[i] = *(const half8*)&As[(i * 16 + l15) * 64 + cg];
            #pragma unroll
            for (int j = 0; j < 4; j++)
                b[j] = *(const half8*)&Ws[(wave * 64 + j * 16 + l15) * 64 + cg];
            #pragma unroll
            for (int i = 0; i < 2; i++)
                #pragma unroll
                for (int j = 0; j < 4; j++)
                    acc[i][j] = __builtin_amdgcn_mfma_f32_16x16x32_f16(a[i], b[j], acc[i][j], 0, 0, 0);
        }
    }
    // ---- epilogue: bias + residual
    int col[4];
    float bv[4], gg1[4], bb1[4], gg2[4], bb2[4];
    #pragma unroll
    for (int j = 0; j < 4; j++) {
        col[j] = wave * 64 + j * 16 + l15;
        bv[j] = bias[col[j]];
        gg1[j] = g1[col[j]]; bb1[j] = b1[col[j]];
        if (FIN == 0) { gg2[j] = g2[col[j]]; bb2[j] = b2[col[j]]; }
    }
    #pragma unroll
    for (int i = 0; i < 2; i++)
        #pragma unroll
        for (int r = 0; r < 4; r++) {
            size_t m = m0 + i * 16 + quad * 4 + r;
            #pragma unroll
            for (int j = 0; j < 4; j++) {
                float xv = res[m * 256 + col[j]] + alpha * (acc[i][j][r] + bv[j]);
                acc[i][j][r] = xv;
                if (FIN == 0) xNext[m * 256 + col[j]] = xv;
            }
        }
    // ---- LN pass 1 stats
    #pragma unroll
    for (int i = 0; i < 2; i++)
        #pragma unroll
        for (int r = 0; r < 4; r++) {
            float s1 = 0.f, s2 = 0.f;
            #pragma unroll
            for (int j = 0; j < 4; j++) { float v = acc[i][j][r]; s1 += v; s2 += v * v; }
            #pragma unroll
            for (int mm = 1; mm < 16; mm <<= 1) { s1 += __shfl_xor(s1, mm, 64); s2 += __shfl_xor(s2, mm, 64); }
            if (l15 == 0) { red[wave][i * 16 + quad * 4 + r][0] = s1; red[wave][i * 16 + quad * 4 + r][1] = s2; }
        }
    __syncthreads();
    float mean1[2][4], rs1[2][4];
    #pragma unroll
    for (int i = 0; i < 2; i++)
        #pragma unroll
        for (int r = 0; r < 4; r++) {
            int row = i * 16 + quad * 4 + r;
            float T1 = red[0][row][0] + red[1][row][0] + red[2][row][0] + red[3][row][0];
            float T2 = red[0][row][1] + red[1][row][1] + red[2][row][1] + red[3][row][1];
            float mn = T1 * (1.f / 256.f);
            mean1[i][r] = mn;
            rs1[i][r] = rsqrtf(T2 * (1.f / 256.f) - mn * mn + LN_EPS);
        }
    if (FIN == 1) {
        #pragma unroll
        for (int i = 0; i < 2; i++)
            #pragma unroll
            for (int r = 0; r < 4; r++) {
                size_t m = m0 + i * 16 + quad * 4 + r;
                #pragma unroll
                for (int j = 0; j < 4; j++)
                    finalOut[m * 256 + col[j]] =
                        (acc[i][j][r] - mean1[i][r]) * rs1[i][r] * gg1[j] + bb1[j];
            }
        return;
    }
    // y1 in-place, then pass 2 stats
    #pragma unroll
    for (int i = 0; i < 2; i++)
        #pragma unroll
        for (int r = 0; r < 4; r++)
            #pragma unroll
            for (int j = 0; j < 4; j++)
                acc[i][j][r] = (acc[i][j][r] - mean1[i][r]) * rs1[i][r] * gg1[j] + bb1[j];
    __syncthreads();
    #pragma unroll
    for (int i = 0; i < 2; i++)
        #pragma unroll
        for (int r = 0; r < 4; r++) {
            float s1 = 0.f, s2 = 0.f;
            #pragma unroll
            for (int j = 0; j < 4; j++) { float v = acc[i][j][r]; s1 += v; s2 += v * v; }
            #pragma unroll
            for (int mm = 1; mm < 16; mm <<= 1) { s1 += __shfl_xor(s1, mm, 64); s2 += __shfl_xor(s2, mm, 64); }
            if (l15 == 0) { red[wave][i * 16 + quad * 4 + r][0] = s1; red[wave][i * 16 + quad * 4 + r][1] = s2; }
        }
    __syncthreads();
    #pragma unroll
    for (int i = 0; i < 2; i++)
        #pragma unroll
        for (int r = 0; r < 4; r++) {
            int row = i * 16 + quad * 4 + r;
            float T1 = red[0][row][0] + red[1][row][0] + red[2][row][0] + red[3][row][0];
            float T2 = red[0][row][1] + red[1][row][1] + red[2][row][1] + red[3][row][1];
            float mn = T1 * (1.f / 256.f);
            float rs = rsqrtf(T2 * (1.f / 256.f) - mn * mn + LN_EPS);
            size_t m = m0 + row;
            #pragma unroll
            for (int j = 0; j < 4; j++)
                t16out[m * 256 + col[j]] =
                    (_Float16)((acc[i][j][r] - mn) * rs * gg2[j] + bb2[j]);
        }
}

// --------------------------------- relative position bias (exp2 domain: *log2e)
__global__ __launch_bounds__(256) void relbias_kernel(const float* __restrict__ rel_w,
                                                      float* __restrict__ rb) {
    int i = blockIdx.x * 256 + threadIdx.x;
    if (i >= 4095 * 4) return;
    int p = i >> 2, h = i & 3;
    float pos = (float)(p - 2047);
    const float c = -logf(10000.f) / 64.f;
    float acc = 0.f;
    for (int k = 0; k < 32; k++) {
        float dv = expf((float)(2 * k) * c);
        float ang = pos * dv;
        acc += sinf(ang) * rel_w[h * 64 + 2 * k] + cosf(ang) * rel_w[h * 64 + 2 * k + 1];
    }
    rb[h * 4095 + p] = acc * LOG2E;
}

// ----------------------------------------------------------- flash attention v6
// 64 q-rows x 64-key tiles, no K-split, grid 1024 = 4 blocks/CU (LDS ~28 KB).
// Q pre-scaled; bias via MFMA C-init; raw v_exp_f32; async global->LDS staging
// for Q/K/V; direct normalized o16 write.
__global__ __launch_bounds__(256) void attn_kernel(const _Float16* __restrict__ qkv,
        const _Float16* __restrict__ vtg, const float* __restrict__ rb,
        _Float16* __restrict__ o16) {
    const int T = 2048;
    int qt = blockIdx.x, h = blockIdx.y, b = blockIdx.z;
    int tid = threadIdx.x, wave = tid >> 6, lane = tid & 63;
    __shared__ __align__(16) _Float16 PQ[4608];           // Qs[64][64] ∪ Ps[4][16][72]
    __shared__ __align__(16) _Float16 Ks[64 * 64];
    __shared__ __align__(16) _Float16 Vt[64 * 64];        // [d][key]
    __shared__ __align__(16) float bias4[4][136];         // bias4[c][i] = w[i+c]
    _Float16* Qs = PQ;                                    // stride 64
    auto Ps = (_Float16(*)[16][72])PQ;

    int l15 = lane & 15, quad = lane >> 4, kq = quad * 8;
    size_t qrow0 = (size_t)b * T + qt * 64;
    #pragma unroll
    for (int i = 0; i < 2; i++) {
        int idx = tid + 256 * i;
        async_copy16(qkv + (qrow0 + (idx >> 3)) * 768 + h * 64 + (idx & 7) * 8, PQ + idx * 8);
    }
    __syncthreads();
    half8 qa[2];
    #pragma unroll
    for (int ks = 0; ks < 2; ks++)
        qa[ks] = *(const half8*)&Qs[(wave * 16 + l15) * 64 + ks * 32 + kq];
    half8 ones;
    #pragma unroll
    for (int j = 0; j < 8; j++) ones[j] = (_Float16)1.f;

    floatx4 oacc[4] = {};
    floatx4 lacc = {};
    const float* rbh = rb + h * 4095;
    const _Float16* vbase = vtg + ((size_t)(b * 4 + h)) * 64 * 2048;
    const _Float16* kbase = qkv + ((size_t)b * T) * 768 + 256 + h * 64;
    int cshift = (63 - l15) & 3;   // lane-constant alignment phase of bias reads

    for (int kt = 0; kt < 32; kt++) {
        __syncthreads();
        #pragma unroll
        for (int i = 0; i < 2; i++) {
            int idx = tid + 256 * i, row = idx >> 3, cg = idx & 7;
            async_copy16(kbase + (size_t)(kt * 64 + row) * 768 + cg * 8, Ks + idx * 8);
            async_copy16(vbase + (size_t)row * 2048 + kt * 64 + cg * 8, Vt + idx * 8);
        }
        if (tid < 136) {
            int base = qt * 64 - kt * 64 + 1984;
            float v = rbh[min(base + tid, 4094)];
            #pragma unroll
            for (int c = 0; c < 4; c++) {
                int idx = tid - c;
                if (idx >= 0) bias4[c][idx] = v;
            }
        }
        __syncthreads();
        // S = bias + Q @ K^T  (bias as C-init; Q pre-scaled by 0.125*log2e)
        half8 kf[2][4];
        #pragma unroll
        for (int ks = 0; ks < 2; ks++)
            #pragma unroll
            for (int nt = 0; nt < 4; nt++)
                kf[ks][nt] = *(const half8*)&Ks[(nt * 16 + l15) * 64 + ks * 32 + kq];
        floatx4 s[4];
        #pragma unroll
        for (int nt = 0; nt < 4; nt++) {
            int cb = wave * 16 + quad * 4 - (nt * 16 + l15) + 63;
            s[nt] = *(const floatx4*)&bias4[cshift][cb - cshift];
        }
        #pragma unroll
        for (int ks = 0; ks < 2; ks++)
            #pragma unroll
            for (int nt = 0; nt < 4; nt++)
                s[nt] = __builtin_amdgcn_mfma_f32_16x16x32_f16(qa[ks], kf[ks][nt], s[nt], 0, 0, 0);
        // p = exp2(s) -> Ps (wave-private, no barrier)
        #pragma unroll
        for (int nt = 0; nt < 4; nt++)
            #pragma unroll
            for (int r = 0; r < 4; r++)
                Ps[wave][quad * 4 + r][nt * 16 + l15] =
                    (_Float16)__builtin_amdgcn_exp2f(fminf(s[nt][r], 15.86f));
        // O += P @ V ; l += P @ 1
        half8 vf[2][4];
        #pragma unroll
        for (int ks = 0; ks < 2; ks++)
            #pragma unroll
            for (int nt = 0; nt < 4; nt++)
                vf[ks][nt] = *(const half8*)&Vt[(nt * 16 + l15) * 64 + ks * 32 + kq];
        #pragma unroll
        for (int ks = 0; ks < 2; ks++) {
            half8 pa = *(const half8*)&Ps[wave][l15][ks * 32 + kq];
            lacc = __builtin_amdgcn_mfma_f32_16x16x32_f16(pa, ones, lacc, 0, 0, 0);
            #pragma unroll
            for (int nt = 0; nt < 4; nt++)
                oacc[nt] = __builtin_amdgcn_mfma_f32_16x16x32_f16(pa, vf[ks][nt], oacc[nt], 0, 0, 0);
        }
    }
    size_t orow0 = qrow0 + wave * 16 + quad * 4;
    #pragma unroll
    for (int r = 0; r < 4; r++) {
        float inv = 1.f / lacc[r];
        #pragma unroll
        for (int nt = 0; nt < 4; nt++)
            o16[(orow0 + r) * 256 + h * 64 + nt * 16 + l15] = (_Float16)(oacc[nt][r] * inv);
    }
}

// -------------------------------------------- depthwise conv 31 + BN + swish
// grid (64,8)=512 blocks, 32 t/block, 4-wide batched prefetch.
__global__ __launch_bounds__(256) void dwconv_kernel(const _Float16* __restrict__ glu,
        const float* __restrict__ dw_w, const float* __restrict__ dw_b,
        const float* __restrict__ bn_g, const float* __restrict__ bn_b,
        _Float16* __restrict__ out) {
    const int T = 2048;
    int d = threadIdx.x;
    int b = blockIdx.y, t0 = blockIdx.x * 32;
    const _Float16* base = glu + ((size_t)b * T) * 256 + d;
    float w[31], win[31];
    #pragma unroll
    for (int j = 0; j < 31; j++) w[j] = dw_w[d * 31 + j];
    #pragma unroll
    for (int j = 0; j < 31; j++) {
        int tt = t0 - 15 + j;
        win[j] = (tt >= 0 && tt < T) ? (float)base[(size_t)tt * 256] : 0.f;
    }
    float dwb = dw_b[d];
    float bns = BN_SCALE * bn_g[d];
    float bnb = bn_b[d];
    size_t orow = ((size_t)b * T) * 256 + d;
    #pragma unroll
    for (int i = 0; i < 32; i += 4) {
        float nl[4];
        #pragma unroll
        for (int u = 0; u < 4; u++) {
            int tn = t0 + i + u + 16;
            nl[u] = (tn < T) ? (float)base[(size_t)tn * 256] : 0.f;
        }
        #pragma unroll
        for (int u = 0; u < 4; u++) {
            int t = t0 + i + u;
            float acc = dwb;
            #pragma unroll
            for (int j = 0; j < 31; j++) acc += win[j] * w[j];
            float bn = acc * bns + bnb;
            out[orow + (size_t)t * 256] = (_Float16)(bn / (1.f + __expf(-bn)));
            #pragma unroll
            for (int j = 0; j < 30; j++) win[j] = win[j + 1];
            win[30] = nl[u];
        }
    }
}

// ---------------------------------------------------------------------------
extern "C" void kernel_launch(void* const* d_in, const int* in_sizes, int n_in,
                              void* d_out, int out_size, void* d_ws, size_t ws_size,
                              hipStream_t stream) {
    (void)in_sizes; (void)n_in; (void)out_size; (void)ws_size;
    const float* x      = (const float*)d_in[0];
    const float* g_ffn1 = (const float*)d_in[1];
    const float* g_mhsa = (const float*)d_in[2];
    const float* g_conv = (const float*)d_in[3];
    const float* g_ffn2 = (const float*)d_in[4];
    const float* g_out  = (const float*)d_in[5];
    const float* f1_ng  = (const float*)d_in[6];
    const float* f2_ng  = (const float*)d_in[7];
    const float* a_ng   = (const float*)d_in[8];
    const float* c_ng   = (const float*)d_in[9];
    const float* bn_g   = (const float*)d_in[10];
    const float* b_ffn1 = (const float*)d_in[11];
    const float* b_mhsa = (const float*)d_in[12];
    const float* b_conv = (const float*)d_in[13];
    const float* b_ffn2 = (const float*)d_in[14];
    const float* b_out  = (const float*)d_in[15];
    const float* f1_nb  = (const float*)d_in[16];
    const float* f2_nb  = (const float*)d_in[17];
    const float* a_nb   = (const float*)d_in[18];
    const float* c_nb   = (const float*)d_in[19];
    const float* bn_b   = (const float*)d_in[20];
    const float* f1_w1  = (const float*)d_in[21];
    const float* f1_b1  = (const float*)d_in[22];
    const float* f1_w2  = (const float*)d_in[23];
    const float* f1_b2  = (const float*)d_in[24];
    const float* f2_w1  = (const float*)d_in[25];
    const float* f2_b1  = (const float*)d_in[26];
    const float* f2_w2  = (const float*)d_in[27];
    const float* f2_b2  = (const float*)d_in[28];
    const float* qkv_w  = (const float*)d_in[29];
    const float* qkv_b  = (const float*)d_in[30];
    const float* rel_w  = (const float*)d_in[31];
    const float* out_w  = (const float*)d_in[32];
    const float* out_b  = (const float*)d_in[33];
    const float* pw1_w  = (const float*)d_in[34];
    const float* pw1_b  = (const float*)d_in[35];
    const float* dw_w   = (const float*)d_in[36];
    const float* dw_b   = (const float*)d_in[37];
    const float* pw2_w  = (const float*)d_in[38];
    const float* pw2_b  = (const float*)d_in[39];

    const int BT = 16384;
    char* ws = (char*)d_ws;
    size_t off = 0;
    auto alloc = [&](size_t bytes) -> char* {
        char* p = ws + off;
        off += (bytes + 255) & ~(size_t)255;
        return p;
    };
    _Float16* wf1w1 = (_Float16*)alloc(262144 * 2);
    _Float16* wf1w2 = (_Float16*)alloc(262144 * 2);
    _Float16* wf2w1 = (_Float16*)alloc(262144 * 2);
    _Float16* wf2w2 = (_Float16*)alloc(262144 * 2);
    _Float16* wqkv  = (_Float16*)alloc(196608 * 2);
    _Float16* wout  = (_Float16*)alloc(65536 * 2);
    _Float16* wpw1  = (_Float16*)alloc(131072 * 2);
    float* pb1      = (float*)alloc(512 * 4);
    _Float16* wpw2  = (_Float16*)alloc(65536 * 2);
    float* rbbuf    = (float*)alloc(4 * 4095 * 4);
    float* xA       = (float*)alloc((size_t)BT * 256 * 4);
    float* xB       = (float*)alloc((size_t)BT * 256 * 4);
    _Float16* t16   = (_Float16*)alloc((size_t)BT * 256 * 2);
    char* R1        = alloc((size_t)BT * 1024 * 2);  // h16 (32MB) / qkv16 (24MB)
    _Float16* vtg   = (_Float16*)alloc((size_t)8 * 4 * 64 * 2048 * 2);  // V^T [b,h,d][t]
    _Float16* glu16 = (_Float16*)alloc((size_t)BT * 256 * 2);
    _Float16* c16   = (_Float16*)alloc((size_t)BT * 256 * 2);
    _Float16* o16   = (_Float16*)alloc((size_t)BT * 256 * 2);
    _Float16* h16   = (_Float16*)R1;
    _Float16* qkv16 = (_Float16*)R1;

    // fused weight casts + pw1 permute + rel-pos bias table
    CastJobs cj;
    cj.s[0] = f1_w1; cj.d[0] = wf1w1;
    cj.s[1] = f1_w2; cj.d[1] = wf1w2;
    cj.s[2] = f2_w1; cj.d[2] = wf2w1;
    cj.s[3] = f2_w2; cj.d[3] = wf2w2;
    cj.s[4] = qkv_w; cj.d[4] = wqkv;
    cj.s[5] = out_w; cj.d[5] = wout;
    cj.s[6] = pw2_w; cj.d[6] = wpw2;
    cast_all<<<5376, 256, 0, stream>>>(cj);
    cast_pw1_kernel<<<512, 256, 0, stream>>>(pw1_w, pw1_b, wpw1, pb1);
    relbias_kernel<<<64, 256, 0, stream>>>(rel_w, rbbuf);

    // ---- FFN1: x1 = x + 0.5*FFN(LN2(x)); fused: t16 = LN2(x1) for MHSA
    ln2_kernel<<<BT / 4, 256, 0, stream>>>(x, g_ffn1, b_ffn1, f1_ng, f1_nb, t16);
    gemm128<1><<<dim3(8, 128), 256, 0, stream>>>(t16, wf1w1, f1_b1, h16, nullptr, 1024, 256);
    gemm_row<0><<<512, 256, 0, stream>>>(h16, wf1w2, f1_b2, x, 0.5f, xA, t16, nullptr,
                                         g_mhsa, b_mhsa, a_ng, a_nb, 1024);
    // ---- MHSA: x2 = x1 + Attn(t16); fused: t16 = LN2(x2) for Conv
    gemm128<5><<<dim3(6, 128), 256, 0, stream>>>(t16, wqkv, qkv_b, qkv16, vtg, 768, 256);
    attn_kernel<<<dim3(32, 4, 8), 256, 0, stream>>>(qkv16, vtg, rbbuf, o16);
    gemm_row<0><<<512, 256, 0, stream>>>(o16, wout, out_b, xA, 1.f, xB, t16, nullptr,
                                         g_conv, b_conv, c_ng, c_nb, 256);
    // ---- Conv: x3 = x2 + Conv(t16); fused: t16 = LN2(x3) for FFN2
    gemm128<2><<<dim3(4, 128), 256, 0, stream>>>(t16, wpw1, pb1, glu16, nullptr, 512, 256);
    dwconv_kernel<<<dim3(64, 8), 256, 0, stream>>>(glu16, dw_w, dw_b, bn_g, bn_b, c16);
    gemm_row<0><<<512, 256, 0, stream>>>(c16, wpw2, pw2_b, xB, 1.f, xA, t16, nullptr,
                                         g_ffn2, b_ffn2, f2_ng, f2_nb, 256);
    // ---- FFN2 + final LN: out = LN(x3 + 0.5*FFN(t16))
    gemm128<1><<<dim3(8, 128), 256, 0, stream>>>(t16, wf2w1, f2_b1, h16, nullptr, 1024, 256);
    gemm_row<1><<<512, 256, 0, stream>>>(h16, wf2w2, f2_b2, xA, 0.5f, nullptr, nullptr,
                                         (float*)d_out, g_out, b_out, nullptr, nullptr, 1024);
}

// Round 9
// 430.268 us; speedup vs baseline: 1.1304x; 1.0577x over previous
//
#include <hip/hip_runtime.h>
#include <math.h>

// ---------------------------------------------------------------------------
// ConformerBlock on MI355X (gfx950). fp32 I/O, fp16 MFMA internals.
// B=8 T=2048 D=256 H=4 hd=64 F=1024 K=31, BT=16384.
// LDS banking: all MFMA staging buffers use XOR-swizzled column groups
// (swizzle applied on the GLOBAL fetch side since global_load_lds scatters
// lane-contiguously): LDS slot (row, cg) holds global (row, cg ^ (row&7));
// fragment reads XOR the same key. 2-way max -> free (m136).
// ---------------------------------------------------------------------------

typedef _Float16 half8 __attribute__((ext_vector_type(8)));
typedef _Float16 half4v __attribute__((ext_vector_type(4)));
typedef float floatx4 __attribute__((ext_vector_type(4)));

#define LN_EPS 1e-5f
#define BN_SCALE 0.9999950000374996f   // 1/sqrt(1+1e-5)
#define LOG2E 1.44269504f
#define QSCALE (0.125f * LOG2E)        // folded into Q at QKV epilogue

__device__ __forceinline__ void async_copy16(const _Float16* g, _Float16* l) {
    __builtin_amdgcn_global_load_lds(
        (const __attribute__((address_space(1))) void*)g,
        (__attribute__((address_space(3))) void*)l, 16, 0, 0);
}

// ---------------------------------------------------- fused weight casts f32->f16
struct CastJobs { const float* s[7]; _Float16* d[7]; };
// segs: 4 x 262144 | qkv 196608 | out 65536 | pw2 65536  (total 1376256)
__global__ __launch_bounds__(256) void cast_all(CastJobs j) {
    int i = blockIdx.x * 256 + threadIdx.x;
    int seg, base;
    if (i < 1048576)      { seg = i >> 18; base = seg << 18; }
    else if (i < 1245184) { seg = 4; base = 1048576; }
    else if (i < 1310720) { seg = 5; base = 1245184; }
    else                  { seg = 6; base = 1310720; }
    j.d[seg][i - base] = (_Float16)j.s[seg][i - base];
}

// Permuted cast for pw1: rows interleaved in 16-row chunks [a0-15, g0-15, a16-31, ...]
__global__ __launch_bounds__(256) void cast_pw1_kernel(const float* __restrict__ w,
        const float* __restrict__ b, _Float16* __restrict__ wp, float* __restrict__ bp) {
    int i = blockIdx.x * 256 + threadIdx.x;   // 512*256 elems
    int p = i >> 8, c = i & 255;
    int chunk = p >> 4, within = p & 15;
    int orig = ((chunk & 1) ? 256 : 0) + (chunk >> 1) * 16 + within;
    wp[i] = (_Float16)w[orig * 256 + c];
    if (c == 0) bp[p] = b[orig];
}

// ------------------------------------------------------- double LayerNorm -> f16
__global__ __launch_bounds__(256) void ln2_kernel(const float* __restrict__ x,
        const float* __restrict__ g1, const float* __restrict__ b1,
        const float* __restrict__ g2, const float* __restrict__ b2,
        _Float16* __restrict__ y) {
    int wave = threadIdx.x >> 6, lane = threadIdx.x & 63;
    size_t row = (size_t)blockIdx.x * 4 + wave;
    float4 v = ((const float4*)(x + row * 256))[lane];
    float s = v.x + v.y + v.z + v.w;
    float s2 = v.x * v.x + v.y * v.y + v.z * v.z + v.w * v.w;
    #pragma unroll
    for (int m = 1; m < 64; m <<= 1) { s += __shfl_xor(s, m, 64); s2 += __shfl_xor(s2, m, 64); }
    float mean = s * (1.f / 256.f);
    float var = s2 * (1.f / 256.f) - mean * mean;
    float rs = rsqrtf(var + LN_EPS);
    int c0 = lane * 4;
    float y0 = (v.x - mean) * rs * g1[c0 + 0] + b1[c0 + 0];
    float y1 = (v.y - mean) * rs * g1[c0 + 1] + b1[c0 + 1];
    float y2 = (v.z - mean) * rs * g1[c0 + 2] + b1[c0 + 2];
    float y3 = (v.w - mean) * rs * g1[c0 + 3] + b1[c0 + 3];
    float t = y0 + y1 + y2 + y3;
    float t2 = y0 * y0 + y1 * y1 + y2 * y2 + y3 * y3;
    #pragma unroll
    for (int m = 1; m < 64; m <<= 1) { t += __shfl_xor(t, m, 64); t2 += __shfl_xor(t2, m, 64); }
    float mean2 = t * (1.f / 256.f);
    float var2 = t2 * (1.f / 256.f) - mean2 * mean2;
    float rs2 = rsqrtf(var2 + LN_EPS);
    half4v o;
    o[0] = (_Float16)((y0 - mean2) * rs2 * g2[c0 + 0] + b2[c0 + 0]);
    o[1] = (_Float16)((y1 - mean2) * rs2 * g2[c0 + 1] + b2[c0 + 1]);
    o[2] = (_Float16)((y2 - mean2) * rs2 * g2[c0 + 2] + b2[c0 + 2]);
    o[3] = (_Float16)((y3 - mean2) * rs2 * g2[c0 + 3] + b2[c0 + 3]);
    *(half4v*)(y + row * 256 + c0) = o;
}

// ---------------------------------------------------------------- GEMM (MFMA)
// 128x128 tile, BK=64, global_load_lds width-16, XOR-swizzled LDS col-groups.
// EPI: 1 = swish->f16 | 2 = GLU(permuted pw1)->f16
//      5 = qkv: n<256 Q*QSCALE f16, n<512 K f16, n>=512 V^T half4 -> outv
template <int EPI>
__global__ __launch_bounds__(256) void gemm128(
        const _Float16* __restrict__ A, const _Float16* __restrict__ W,
        const float* __restrict__ bias, _Float16* __restrict__ outh,
        _Float16* __restrict__ outv, int N, int K) {
    __shared__ _Float16 As[128 * 64];
    __shared__ _Float16 Ws[128 * 64];
    int tid = threadIdx.x, wave = tid >> 6, lane = tid & 63;
    int n0 = blockIdx.x * 128, m0 = blockIdx.y * 128;
    int wr = wave >> 1, wc = wave & 1;
    floatx4 acc[4][4] = {};
    int l15 = lane & 15, quad = lane >> 4;
    int srow = wave * 32 + (lane >> 3);
    int scg  = (lane & 7) ^ ((lane >> 3) & 7);       // swizzled global col-group
    const _Float16* Aptr = A + (size_t)(m0 + srow) * K + scg * 8;
    const _Float16* Wptr = W + (size_t)(n0 + srow) * K + scg * 8;
    _Float16* AsBase = As + wave * 32 * 64;
    _Float16* WsBase = Ws + wave * 32 * 64;
    int r7 = l15 & 7;                                 // read-side swizzle key
    for (int k0 = 0; k0 < K; k0 += 64) {
        __syncthreads();
        #pragma unroll
        for (int i = 0; i < 4; i++)
            async_copy16(Aptr + k0 + (size_t)i * 8 * K, AsBase + i * 8 * 64);
        #pragma unroll
        for (int i = 0; i < 4; i++)
            async_copy16(Wptr + k0 + (size_t)i * 8 * K, WsBase + i * 8 * 64);
        __syncthreads();
        #pragma unroll
        for (int ks = 0; ks < 2; ks++) {
            int cg = ((ks * 4 + quad) ^ r7) * 8;
            half8 a[4], b[4];
            #pragma unroll
            for (int i = 0; i < 4; i++)
                a[i] = *(const half8*)&As[(wr * 64 + i * 16 + l15) * 64 + cg];
            #pragma unroll
            for (int j = 0; j < 4; j++)
                b[j] = *(const half8*)&Ws[(wc * 64 + j * 16 + l15) * 64 + cg];
            #pragma unroll
            for (int i = 0; i < 4; i++)
                #pragma unroll
                for (int j = 0; j < 4; j++)
                    acc[i][j] = __builtin_amdgcn_mfma_f32_16x16x32_f16(a[i], b[j], acc[i][j], 0, 0, 0);
        }
    }
    #pragma unroll
    for (int i = 0; i < 4; i++) {
        int mrow = m0 + wr * 64 + i * 16 + quad * 4;
        if (EPI == 2) {
            #pragma unroll
            for (int jp = 0; jp < 2; jp++) {
                int j = 2 * jp;
                int Pa = n0 + wc * 64 + j * 16 + l15;
                float ba = bias[Pa], bg = bias[Pa + 16];
                int d = ((Pa >> 5) << 4) + l15;
                #pragma unroll
                for (int r = 0; r < 4; r++) {
                    float av = acc[i][j][r] + ba;
                    float gv = acc[i][j + 1][r] + bg;
                    outh[(size_t)(mrow + r) * 256 + d] = (_Float16)(av / (1.f + __expf(-gv)));
                }
            }
        } else if (EPI == 5) {
            float qs = (n0 < 256) ? QSCALE : 1.f;
            #pragma unroll
            for (int j = 0; j < 4; j++) {
                int n = n0 + wc * 64 + j * 16 + l15;
                float bv = bias[n];
                if (n0 < 512) {
                    #pragma unroll
                    for (int r = 0; r < 4; r++)
                        outh[(size_t)(mrow + r) * N + n] = (_Float16)((acc[i][j][r] + bv) * qs);
                } else {
                    int hv = (n - 512) >> 6, d = (n - 512) & 63;
                    int bb = m0 >> 11;
                    int t0 = (m0 & 2047) + wr * 64 + i * 16 + quad * 4;
                    half4v vv;
                    #pragma unroll
                    for (int r = 0; r < 4; r++) vv[r] = (_Float16)(acc[i][j][r] + bv);
                    *(half4v*)(outv + ((size_t)((bb * 4 + hv) * 64 + d)) * 2048 + t0) = vv;
                }
            }
        } else {  // EPI == 1 swish
            #pragma unroll
            for (int j = 0; j < 4; j++) {
                int n = n0 + wc * 64 + j * 16 + l15;
                float bv = bias[n];
                #pragma unroll
                for (int r = 0; r < 4; r++) {
                    float c = acc[i][j][r] + bv;
                    outh[(size_t)(mrow + r) * N + n] = (_Float16)(c / (1.f + __expf(-c)));
                }
            }
        }
    }
}

// ------------------------------------------------- full-row reducer GEMM (N=256)
// tile 32x256 (4 waves x 32x64), grid 512 = 2 blocks/CU. Epilogue: c += bias;
// x = res + alpha*c;
// FIN=0: write xNext f32, then t16 = LN(LN(x; g1,b1); g2,b2) f16.
// FIN=1: write finalOut f32 = LN(x; g1,b1)  (d_out path, no xNext).
template <int FIN>
__global__ __launch_bounds__(256) void gemm_row(
        const _Float16* __restrict__ A, const _Float16* __restrict__ W,
        const float* __restrict__ bias, const float* __restrict__ res, float alpha,
        float* __restrict__ xNext, _Float16* __restrict__ t16out,
        float* __restrict__ finalOut,
        const float* __restrict__ g1, const float* __restrict__ b1,
        const float* __restrict__ g2, const float* __restrict__ b2, int K) {
    __shared__ _Float16 As[32 * 64];    // 4 KB
    __shared__ _Float16 Ws[256 * 64];   // 32 KB
    __shared__ float red[4][32][2];     // per-wave per-row (s1,s2)
    int tid = threadIdx.x, wave = tid >> 6, lane = tid & 63;
    int l15 = lane & 15, quad = lane >> 4;
    int m0 = blockIdx.x * 32;
    int sgsw = (tid & 7) ^ ((tid >> 3) & 7);          // swizzled global col-group
    int r7 = l15 & 7;
    floatx4 acc[2][4] = {};
    for (int k0 = 0; k0 < K; k0 += 64) {
        __syncthreads();
        async_copy16(A + (size_t)(m0 + (tid >> 3)) * K + k0 + sgsw * 8, As + tid * 8);
        #pragma unroll
        for (int i = 0; i < 8; i++) {
            int idx = tid + 256 * i;
            async_copy16(W + (size_t)(idx >> 3) * K + k0 + sgsw * 8, Ws + idx * 8);
        }
        __syncthreads();
        #pragma unroll
        for (int ks = 0; ks < 2; ks++) {
            int cg = ((ks * 4 + quad) ^ r7) * 8;
            half8 a[2], b[4];
            #pragma unroll
            for (int i = 0; i < 2; i++)
                a[i] = *(const half8*)&As[(i * 16 + l15) * 64 + cg];
            #pragma unroll
            for (int j = 0; j < 4; j++)
                b[j] = *(const half8*)&Ws[(wave * 64 + j * 16 + l15) * 64 + cg];
            #pragma unroll
            for (int i = 0; i < 2; i++)
                #pragma unroll
                for (int j = 0; j < 4; j++)
                    acc[i][j] = __builtin_amdgcn_mfma_f32_16x16x32_f16(a[i], b[j], acc[i][j], 0, 0, 0);
        }
    }
    // ---- epilogue: bias + residual
    int col[4];
    float bv[4], gg1[4], bb1[4], gg2[4], bb2[4];
    #pragma unroll
    for (int j = 0; j < 4; j++) {
        col[j] = wave * 64 + j * 16 + l15;
        bv[j] = bias[col[j]];
        gg1[j] = g1[col[j]]; bb1[j] = b1[col[j]];
        if (FIN == 0) { gg2[j] = g2[col[j]]; bb2[j] = b2[col[j]]; }
    }
    #pragma unroll
    for (int i = 0; i < 2; i++)
        #pragma unroll
        for (int r = 0; r < 4; r++) {
            size_t m = m0 + i * 16 + quad * 4 + r;
            #pragma unroll
            for (int j = 0; j < 4; j++) {
                float xv = res[m * 256 + col[j]] + alpha * (acc[i][j][r] + bv[j]);
                acc[i][j][r] = xv;
                if (FIN == 0) xNext[m * 256 + col[j]] = xv;
            }
        }
    // ---- LN pass 1 stats
    #pragma unroll
    for (int i = 0; i < 2; i++)
        #pragma unroll
        for (int r = 0; r < 4; r++) {
            float s1 = 0.f, s2 = 0.f;
            #pragma unroll
            for (int j = 0; j < 4; j++) { float v = acc[i][j][r]; s1 += v; s2 += v * v; }
            #pragma unroll
            for (int mm = 1; mm < 16; mm <<= 1) { s1 += __shfl_xor(s1, mm, 64); s2 += __shfl_xor(s2, mm, 64); }
            if (l15 == 0) { red[wave][i * 16 + quad * 4 + r][0] = s1; red[wave][i * 16 + quad * 4 + r][1] = s2; }
        }
    __syncthreads();
    float mean1[2][4], rs1[2][4];
    #pragma unroll
    for (int i = 0; i < 2; i++)
        #pragma unroll
        for (int r = 0; r < 4; r++) {
            int row = i * 16 + quad * 4 + r;
            float T1 = red[0][row][0] + red[1][row][0] + red[2][row][0] + red[3][row][0];
            float T2 = red[0][row][1] + red[1][row][1] + red[2][row][1] + red[3][row][1];
            float mn = T1 * (1.f / 256.f);
            mean1[i][r] = mn;
            rs1[i][r] = rsqrtf(T2 * (1.f / 256.f) - mn * mn + LN_EPS);
        }
    if (FIN == 1) {
        #pragma unroll
        for (int i = 0; i < 2; i++)
            #pragma unroll
            for (int r = 0; r < 4; r++) {
                size_t m = m0 + i * 16 + quad * 4 + r;
                #pragma unroll
                for (int j = 0; j < 4; j++)
                    finalOut[m * 256 + col[j]] =
                        (acc[i][j][r] - mean1[i][r]) * rs1[i][r] * gg1[j] + bb1[j];
            }
        return;
    }
    // y1 in-place, then pass 2 stats
    #pragma unroll
    for (int i = 0; i < 2; i++)
        #pragma unroll
        for (int r = 0; r < 4; r++)
            #pragma unroll
            for (int j = 0; j < 4; j++)
                acc[i][j][r] = (acc[i][j][r] - mean1[i][r]) * rs1[i][r] * gg1[j] + bb1[j];
    __syncthreads();
    #pragma unroll
    for (int i = 0; i < 2; i++)
        #pragma unroll
        for (int r = 0; r < 4; r++) {
            float s1 = 0.f, s2 = 0.f;
            #pragma unroll
            for (int j = 0; j < 4; j++) { float v = acc[i][j][r]; s1 += v; s2 += v * v; }
            #pragma unroll
            for (int mm = 1; mm < 16; mm <<= 1) { s1 += __shfl_xor(s1, mm, 64); s2 += __shfl_xor(s2, mm, 64); }
            if (l15 == 0) { red[wave][i * 16 + quad * 4 + r][0] = s1; red[wave][i * 16 + quad * 4 + r][1] = s2; }
        }
    __syncthreads();
    #pragma unroll
    for (int i = 0; i < 2; i++)
        #pragma unroll
        for (int r = 0; r < 4; r++) {
            int row = i * 16 + quad * 4 + r;
            float T1 = red[0][row][0] + red[1][row][0] + red[2][row][0] + red[3][row][0];
            float T2 = red[0][row][1] + red[1][row][1] + red[2][row][1] + red[3][row][1];
            float mn = T1 * (1.f / 256.f);
            float rs = rsqrtf(T2 * (1.f / 256.f) - mn * mn + LN_EPS);
            size_t m = m0 + row;
            #pragma unroll
            for (int j = 0; j < 4; j++)
                t16out[m * 256 + col[j]] =
                    (_Float16)((acc[i][j][r] - mn) * rs * gg2[j] + bb2[j]);
        }
}

// --------------------------------- relative position bias (exp2 domain: *log2e)
__global__ __launch_bounds__(256) void relbias_kernel(const float* __restrict__ rel_w,
                                                      float* __restrict__ rb) {
    int i = blockIdx.x * 256 + threadIdx.x;
    if (i >= 4095 * 4) return;
    int p = i >> 2, h = i & 3;
    float pos = (float)(p - 2047);
    const float c = -logf(10000.f) / 64.f;
    float acc = 0.f;
    for (int k = 0; k < 32; k++) {
        float dv = expf((float)(2 * k) * c);
        float ang = pos * dv;
        acc += sinf(ang) * rel_w[h * 64 + 2 * k] + cosf(ang) * rel_w[h * 64 + 2 * k + 1];
    }
    rb[h * 4095 + p] = acc * LOG2E;
}

// ----------------------------------------------------------- flash attention v7
// 64 q-rows x 64-key tiles, grid 1024 = 4 blocks/CU (LDS ~28 KB). Async staging
// with XOR-swizzled col-groups for Q/K/V (kills the v6 16-way read conflicts).
// Q pre-scaled; bias via MFMA C-init; raw v_exp_f32; direct o16 write.
__global__ __launch_bounds__(256) void attn_kernel(const _Float16* __restrict__ qkv,
        const _Float16* __restrict__ vtg, const float* __restrict__ rb,
        _Float16* __restrict__ o16) {
    const int T = 2048;
    int qt = blockIdx.x, h = blockIdx.y, b = blockIdx.z;
    int tid = threadIdx.x, wave = tid >> 6, lane = tid & 63;
    __shared__ __align__(16) _Float16 PQ[4608];           // Qs[64][64] ∪ Ps[4][16][72]
    __shared__ __align__(16) _Float16 Ks[64 * 64];
    __shared__ __align__(16) _Float16 Vt[64 * 64];        // [d][key]
    __shared__ __align__(16) float bias4[4][136];         // bias4[c][i] = w[i+c]
    _Float16* Qs = PQ;                                    // stride 64, swizzled
    auto Ps = (_Float16(*)[16][72])PQ;

    int l15 = lane & 15, quad = lane >> 4, kq = quad * 8;
    int r7 = l15 & 7;                                     // read-side swizzle key
    size_t qrow0 = (size_t)b * T + qt * 64;
    #pragma unroll
    for (int i = 0; i < 2; i++) {
        int idx = tid + 256 * i, row = idx >> 3;
        int cgs = (idx & 7) ^ (row & 7);
        async_copy16(qkv + (qrow0 + row) * 768 + h * 64 + cgs * 8, PQ + idx * 8);
    }
    __syncthreads();
    half8 qa[2];
    #pragma unroll
    for (int ks = 0; ks < 2; ks++)
        qa[ks] = *(const half8*)&Qs[(wave * 16 + l15) * 64 + ((ks * 4 + quad) ^ r7) * 8];
    half8 ones;
    #pragma unroll
    for (int j = 0; j < 8; j++) ones[j] = (_Float16)1.f;

    floatx4 oacc[4] = {};
    floatx4 lacc = {};
    const float* rbh = rb + h * 4095;
    const _Float16* vbase = vtg + ((size_t)(b * 4 + h)) * 64 * 2048;
    const _Float16* kbase = qkv + ((size_t)b * T) * 768 + 256 + h * 64;
    int cshift = (63 - l15) & 3;   // lane-constant alignment phase of bias reads

    for (int kt = 0; kt < 32; kt++) {
        __syncthreads();
        #pragma unroll
        for (int i = 0; i < 2; i++) {
            int idx = tid + 256 * i, row = idx >> 3;
            int cgs = (idx & 7) ^ (row & 7);
            async_copy16(kbase + (size_t)(kt * 64 + row) * 768 + cgs * 8, Ks + idx * 8);
            async_copy16(vbase + (size_t)row * 2048 + kt * 64 + cgs * 8, Vt + idx * 8);
        }
        if (tid < 136) {
            int base = qt * 64 - kt * 64 + 1984;
            float v = rbh[min(base + tid, 4094)];
            #pragma unroll
            for (int c = 0; c < 4; c++) {
                int idx = tid - c;
                if (idx >= 0) bias4[c][idx] = v;
            }
        }
        __syncthreads();
        // S = bias + Q @ K^T  (bias as C-init; Q pre-scaled by 0.125*log2e)
        half8 kf[2][4];
        #pragma unroll
        for (int ks = 0; ks < 2; ks++) {
            int cg = ((ks * 4 + quad) ^ r7) * 8;
            #pragma unroll
            for (int nt = 0; nt < 4; nt++)
                kf[ks][nt] = *(const half8*)&Ks[(nt * 16 + l15) * 64 + cg];
        }
        floatx4 s[4];
        #pragma unroll
        for (int nt = 0; nt < 4; nt++) {
            int cb = wave * 16 + quad * 4 - (nt * 16 + l15) + 63;
            s[nt] = *(const floatx4*)&bias4[cshift][cb - cshift];
        }
        #pragma unroll
        for (int ks = 0; ks < 2; ks++)
            #pragma unroll
            for (int nt = 0; nt < 4; nt++)
                s[nt] = __builtin_amdgcn_mfma_f32_16x16x32_f16(qa[ks], kf[ks][nt], s[nt], 0, 0, 0);
        // p = exp2(s) -> Ps (wave-private, padded 72, no barrier)
        #pragma unroll
        for (int nt = 0; nt < 4; nt++)
            #pragma unroll
            for (int r = 0; r < 4; r++)
                Ps[wave][quad * 4 + r][nt * 16 + l15] =
                    (_Float16)__builtin_amdgcn_exp2f(fminf(s[nt][r], 15.86f));
        // O += P @ V ; l += P @ 1
        half8 vf[2][4];
        #pragma unroll
        for (int ks = 0; ks < 2; ks++) {
            int cg = ((ks * 4 + quad) ^ r7) * 8;
            #pragma unroll
            for (int nt = 0; nt < 4; nt++)
                vf[ks][nt] = *(const half8*)&Vt[(nt * 16 + l15) * 64 + cg];
        }
        #pragma unroll
        for (int ks = 0; ks < 2; ks++) {
            half8 pa = *(const half8*)&Ps[wave][l15][ks * 32 + kq];
            lacc = __builtin_amdgcn_mfma_f32_16x16x32_f16(pa, ones, lacc, 0, 0, 0);
            #pragma unroll
            for (int nt = 0; nt < 4; nt++)
                oacc[nt] = __builtin_amdgcn_mfma_f32_16x16x32_f16(pa, vf[ks][nt], oacc[nt], 0, 0, 0);
        }
    }
    size_t orow0 = qrow0 + wave * 16 + quad * 4;
    #pragma unroll
    for (int r = 0; r < 4; r++) {
        float inv = 1.f / lacc[r];
        #pragma unroll
        for (int nt = 0; nt < 4; nt++)
            o16[(orow0 + r) * 256 + h * 64 + nt * 16 + l15] = (_Float16)(oacc[nt][r] * inv);
    }
}

// -------------------------------------------- depthwise conv 31 + BN + swish
// grid (64,8)=512 blocks, 32 t/block, 4-wide batched prefetch.
__global__ __launch_bounds__(256) void dwconv_kernel(const _Float16* __restrict__ glu,
        const float* __restrict__ dw_w, const float* __restrict__ dw_b,
        const float* __restrict__ bn_g, const float* __restrict__ bn_b,
        _Float16* __restrict__ out) {
    const int T = 2048;
    int d = threadIdx.x;
    int b = blockIdx.y, t0 = blockIdx.x * 32;
    const _Float16* base = glu + ((size_t)b * T) * 256 + d;
    float w[31], win[31];
    #pragma unroll
    for (int j = 0; j < 31; j++) w[j] = dw_w[d * 31 + j];
    #pragma unroll
    for (int j = 0; j < 31; j++) {
        int tt = t0 - 15 + j;
        win[j] = (tt >= 0 && tt < T) ? (float)base[(size_t)tt * 256] : 0.f;
    }
    float dwb = dw_b[d];
    float bns = BN_SCALE * bn_g[d];
    float bnb = bn_b[d];
    size_t orow = ((size_t)b * T) * 256 + d;
    #pragma unroll
    for (int i = 0; i < 32; i += 4) {
        float nl[4];
        #pragma unroll
        for (int u = 0; u < 4; u++) {
            int tn = t0 + i + u + 16;
            nl[u] = (tn < T) ? (float)base[(size_t)tn * 256] : 0.f;
        }
        #pragma unroll
        for (int u = 0; u < 4; u++) {
            int t = t0 + i + u;
            float acc = dwb;
            #pragma unroll
            for (int j = 0; j < 31; j++) acc += win[j] * w[j];
            float bn = acc * bns + bnb;
            out[orow + (size_t)t * 256] = (_Float16)(bn / (1.f + __expf(-bn)));
            #pragma unroll
            for (int j = 0; j < 30; j++) win[j] = win[j + 1];
            win[30] = nl[u];
        }
    }
}

// ---------------------------------------------------------------------------
extern "C" void kernel_launch(void* const* d_in, const int* in_sizes, int n_in,
                              void* d_out, int out_size, void* d_ws, size_t ws_size,
                              hipStream_t stream) {
    (void)in_sizes; (void)n_in; (void)out_size; (void)ws_size;
    const float* x      = (const float*)d_in[0];
    const float* g_ffn1 = (const float*)d_in[1];
    const float* g_mhsa = (const float*)d_in[2];
    const float* g_conv = (const float*)d_in[3];
    const float* g_ffn2 = (const float*)d_in[4];
    const float* g_out  = (const float*)d_in[5];
    const float* f1_ng  = (const float*)d_in[6];
    const float* f2_ng  = (const float*)d_in[7];
    const float* a_ng   = (const float*)d_in[8];
    const float* c_ng   = (const float*)d_in[9];
    const float* bn_g   = (const float*)d_in[10];
    const float* b_ffn1 = (const float*)d_in[11];
    const float* b_mhsa = (const float*)d_in[12];
    const float* b_conv = (const float*)d_in[13];
    const float* b_ffn2 = (const float*)d_in[14];
    const float* b_out  = (const float*)d_in[15];
    const float* f1_nb  = (const float*)d_in[16];
    const float* f2_nb  = (const float*)d_in[17];
    const float* a_nb   = (const float*)d_in[18];
    const float* c_nb   = (const float*)d_in[19];
    const float* bn_b   = (const float*)d_in[20];
    const float* f1_w1  = (const float*)d_in[21];
    const float* f1_b1  = (const float*)d_in[22];
    const float* f1_w2  = (const float*)d_in[23];
    const float* f1_b2  = (const float*)d_in[24];
    const float* f2_w1  = (const float*)d_in[25];
    const float* f2_b1  = (const float*)d_in[26];
    const float* f2_w2  = (const float*)d_in[27];
    const float* f2_b2  = (const float*)d_in[28];
    const float* qkv_w  = (const float*)d_in[29];
    const float* qkv_b  = (const float*)d_in[30];
    const float* rel_w  = (const float*)d_in[31];
    const float* out_w  = (const float*)d_in[32];
    const float* out_b  = (const float*)d_in[33];
    const float* pw1_w  = (const float*)d_in[34];
    const float* pw1_b  = (const float*)d_in[35];
    const float* dw_w   = (const float*)d_in[36];
    const float* dw_b   = (const float*)d_in[37];
    const float* pw2_w  = (const float*)d_in[38];
    const float* pw2_b  = (const float*)d_in[39];

    const int BT = 16384;
    char* ws = (char*)d_ws;
    size_t off = 0;
    auto alloc = [&](size_t bytes) -> char* {
        char* p = ws + off;
        off += (bytes + 255) & ~(size_t)255;
        return p;
    };
    _Float16* wf1w1 = (_Float16*)alloc(262144 * 2);
    _Float16* wf1w2 = (_Float16*)alloc(262144 * 2);
    _Float16* wf2w1 = (_Float16*)alloc(262144 * 2);
    _Float16* wf2w2 = (_Float16*)alloc(262144 * 2);
    _Float16* wqkv  = (_Float16*)alloc(196608 * 2);
    _Float16* wout  = (_Float16*)alloc(65536 * 2);
    _Float16* wpw1  = (_Float16*)alloc(131072 * 2);
    float* pb1      = (float*)alloc(512 * 4);
    _Float16* wpw2  = (_Float16*)alloc(65536 * 2);
    float* rbbuf    = (float*)alloc(4 * 4095 * 4);
    float* xA       = (float*)alloc((size_t)BT * 256 * 4);
    float* xB       = (float*)alloc((size_t)BT * 256 * 4);
    _Float16* t16   = (_Float16*)alloc((size_t)BT * 256 * 2);
    char* R1        = alloc((size_t)BT * 1024 * 2);  // h16 (32MB) / qkv16 (24MB)
    _Float16* vtg   = (_Float16*)alloc((size_t)8 * 4 * 64 * 2048 * 2);  // V^T [b,h,d][t]
    _Float16* glu16 = (_Float16*)alloc((size_t)BT * 256 * 2);
    _Float16* c16   = (_Float16*)alloc((size_t)BT * 256 * 2);
    _Float16* o16   = (_Float16*)alloc((size_t)BT * 256 * 2);
    _Float16* h16   = (_Float16*)R1;
    _Float16* qkv16 = (_Float16*)R1;

    // fused weight casts + pw1 permute + rel-pos bias table
    CastJobs cj;
    cj.s[0] = f1_w1; cj.d[0] = wf1w1;
    cj.s[1] = f1_w2; cj.d[1] = wf1w2;
    cj.s[2] = f2_w1; cj.d[2] = wf2w1;
    cj.s[3] = f2_w2; cj.d[3] = wf2w2;
    cj.s[4] = qkv_w; cj.d[4] = wqkv;
    cj.s[5] = out_w; cj.d[5] = wout;
    cj.s[6] = pw2_w; cj.d[6] = wpw2;
    cast_all<<<5376, 256, 0, stream>>>(cj);
    cast_pw1_kernel<<<512, 256, 0, stream>>>(pw1_w, pw1_b, wpw1, pb1);
    relbias_kernel<<<64, 256, 0, stream>>>(rel_w, rbbuf);

    // ---- FFN1: x1 = x + 0.5*FFN(LN2(x)); fused: t16 = LN2(x1) for MHSA
    ln2_kernel<<<BT / 4, 256, 0, stream>>>(x, g_ffn1, b_ffn1, f1_ng, f1_nb, t16);
    gemm128<1><<<dim3(8, 128), 256, 0, stream>>>(t16, wf1w1, f1_b1, h16, nullptr, 1024, 256);
    gemm_row<0><<<512, 256, 0, stream>>>(h16, wf1w2, f1_b2, x, 0.5f, xA, t16, nullptr,
                                         g_mhsa, b_mhsa, a_ng, a_nb, 1024);
    // ---- MHSA: x2 = x1 + Attn(t16); fused: t16 = LN2(x2) for Conv
    gemm128<5><<<dim3(6, 128), 256, 0, stream>>>(t16, wqkv, qkv_b, qkv16, vtg, 768, 256);
    attn_kernel<<<dim3(32, 4, 8), 256, 0, stream>>>(qkv16, vtg, rbbuf, o16);
    gemm_row<0><<<512, 256, 0, stream>>>(o16, wout, out_b, xA, 1.f, xB, t16, nullptr,
                                         g_conv, b_conv, c_ng, c_nb, 256);
    // ---- Conv: x3 = x2 + Conv(t16); fused: t16 = LN2(x3) for FFN2
    gemm128<2><<<dim3(4, 128), 256, 0, stream>>>(t16, wpw1, pb1, glu16, nullptr, 512, 256);
    dwconv_kernel<<<dim3(64, 8), 256, 0, stream>>>(glu16, dw_w, dw_b, bn_g, bn_b, c16);
    gemm_row<0><<<512, 256, 0, stream>>>(c16, wpw2, pw2_b, xB, 1.f, xA, t16, nullptr,
                                         g_ffn2, b_ffn2, f2_ng, f2_nb, 256);
    // ---- FFN2 + final LN: out = LN(x3 + 0.5*FFN(t16))
    gemm128<1><<<dim3(8, 128), 256, 0, stream>>>(t16, wf2w1, f2_b1, h16, nullptr, 1024, 256);
    gemm_row<1><<<512, 256, 0, stream>>>(h16, wf2w2, f2_b2, xA, 0.5f, nullptr, nullptr,
                                         (float*)d_out, g_out, b_out, nullptr, nullptr, 1024);
}